// Round 15
// baseline (257.639 us; speedup 1.0000x reference)
//
#include <hip/hip_runtime.h>

#define NB 4
#define SEQ 4096
#define DIM 1024
#define DFF 4096
#define KSEL 2048
#define NTOK (NB * SEQ)   // 16384
#define MR (NB * KSEL)    // 8192

typedef float f32x4_t __attribute__((ext_vector_type(4)));
typedef unsigned long u64_t;
typedef unsigned long u64x2_t __attribute__((ext_vector_type(2)));
typedef int i32x8_t __attribute__((ext_vector_type(8)));

// HW f32->fp8 e4m3 (OCP, RNE, saturating)
__device__ __forceinline__ unsigned char f2fp8(float f) {
  return (unsigned char)(__builtin_amdgcn_cvt_pk_fp8_f32(f, f, 0, false) & 0xff);
}

// fragment-friendly byte permutation within a 128B K-block:
// k = kk*32 + slot*8 + b  ->  pos = slot*32 + kk*8 + b
__device__ __forceinline__ int kperm(int kb) {
  return ((kb >> 3) & 3) * 32 + (kb >> 5) * 8 + (kb & 7);
}

#define GLD16(g, l) __builtin_amdgcn_global_load_lds( \
    (const __attribute__((address_space(1))) void*)(g), \
    (__attribute__((address_space(3))) void*)(l), 16, 0, 0)

// ---- fused prep: W1/W2 transpose+cast (blocks 0..8191) + router GEMV
//      (blocks 8192..12287) -- independent work, one launch ----
__global__ void prep_kernel(const float* __restrict__ W1, unsigned char* __restrict__ W1t,
                            const float* __restrict__ W2, unsigned char* __restrict__ W2t,
                            const float* __restrict__ x, const float* __restrict__ Wr,
                            const float* __restrict__ br,
                            float* __restrict__ logits, float* __restrict__ scores) {
  __shared__ float tl[32][33];
  int bid = blockIdx.x;
  if (bid < 8192) {
    const float* W; unsigned char* Wt; int R, C, bx, by;
    if (bid < 4096) { W = W1; Wt = W1t; R = DIM; C = DFF; bx = bid & 127; by = bid >> 7; }
    else { bid -= 4096; W = W2; Wt = W2t; R = DFF; C = DIM; bx = bid & 31; by = bid >> 5; }
    int c0 = bx * 32;
    int r0 = by * 32;
    int tx = threadIdx.x & 31, ty = threadIdx.x >> 5;
#pragma unroll
    for (int i = 0; i < 4; ++i)
      tl[ty + i * 8][tx] = W[(size_t)(r0 + ty + i * 8) * C + c0 + tx];
    __syncthreads();
    int k = r0 + tx;
    int pos = (k & ~127) + kperm(k & 127);
#pragma unroll
    for (int i = 0; i < 4; ++i)
      Wt[(size_t)(c0 + ty + i * 8) * R + pos] = f2fp8(16.f * tl[tx][ty + i * 8]);
  } else {
    int lane = threadIdx.x & 63;
    int wid  = threadIdx.x >> 6;
    int row  = (bid - 8192) * 4 + wid;        // 0..16383
    const float4* xr = (const float4*)(x + (size_t)row * DIM);
    const float4* w4 = (const float4*)Wr;
    float sum = 0.f;
#pragma unroll
    for (int i = 0; i < 4; ++i) {
      float4 a = xr[lane + i * 64];
      float4 w = w4[lane + i * 64];
      sum += a.x * w.x + a.y * w.y + a.z * w.z + a.w * w.w;
    }
#pragma unroll
    for (int off = 32; off > 0; off >>= 1) sum += __shfl_down(sum, off);
    if (lane == 0) {
      float l = sum + br[0];
      logits[row] = l;
      scores[row] = 1.f / (1.f + expf(-l));
    }
  }
}

// ---- exact top-k via rank counting (matches jax.lax.top_k tie-break) ----
__global__ void rank_kernel(const float* __restrict__ scores, int* __restrict__ sel) {
  __shared__ float s_sc[SEQ];
  int batch = blockIdx.x >> 8;        // 256 blocks per batch
  int chunk = blockIdx.x & 255;
  int t = threadIdx.x;                // 256
  const float4* sb4 = (const float4*)(scores + batch * SEQ);
  float4* ls4 = (float4*)s_sc;
#pragma unroll
  for (int i = 0; i < 4; ++i) ls4[t + i * 256] = sb4[t + i * 256];
  __syncthreads();
  int tok = chunk * 16 + (t >> 4);    // token this thread contributes to
  int sg  = t & 15;                   // score segment 0..15 (256 scores each)
  float s = s_sc[tok];
  const float4* seg = ls4 + sg * 64;
  int jbase = sg * 256;
  int rank = 0;
#pragma unroll 4
  for (int j4 = 0; j4 < 64; ++j4) {
    float4 v = seg[j4];
    int j = jbase + j4 * 4;
    rank += (v.x > s || (v.x == s && j     < tok)) ? 1 : 0;
    rank += (v.y > s || (v.y == s && j + 1 < tok)) ? 1 : 0;
    rank += (v.z > s || (v.z == s && j + 2 < tok)) ? 1 : 0;
    rank += (v.w > s || (v.w == s && j + 3 < tok)) ? 1 : 0;
  }
#pragma unroll
  for (int off = 8; off > 0; off >>= 1) rank += __shfl_down(rank, off, 16);
  if (sg == 0) sel[batch * SEQ + tok] = (rank < KSEL) ? 1 : 0;
}

// ---- per-batch: softmax over selected scores + prefix-sum compaction ----
__global__ void pack_kernel(const float* __restrict__ scores, const int* __restrict__ sel,
                            int* __restrict__ rows, float* __restrict__ rwv,
                            int* __restrict__ slot) {
  __shared__ float red[16];
  __shared__ int scn[1024];
  int batch = blockIdx.x;
  int t = threadIdx.x;
  const float* sb = scores + batch * SEQ;
  const int* fb = sel + batch * SEQ;
  float sc[4]; int fl[4];
#pragma unroll
  for (int i = 0; i < 4; ++i) { sc[i] = sb[t * 4 + i]; fl[i] = fb[t * 4 + i]; }
  float m = fmaxf(fmaxf(sc[0], sc[1]), fmaxf(sc[2], sc[3]));
#pragma unroll
  for (int off = 32; off > 0; off >>= 1) m = fmaxf(m, __shfl_down(m, off));
  if ((t & 63) == 0) red[t >> 6] = m;
  __syncthreads();
  if (t == 0) { float v = red[0]; for (int i = 1; i < 16; ++i) v = fmaxf(v, red[i]); red[0] = v; }
  __syncthreads();
  m = red[0];
  __syncthreads();
  float ex[4]; float esum = 0.f;
#pragma unroll
  for (int i = 0; i < 4; ++i) { ex[i] = expf(sc[i] - m); if (fl[i]) esum += ex[i]; }
#pragma unroll
  for (int off = 32; off > 0; off >>= 1) esum += __shfl_down(esum, off);
  if ((t & 63) == 0) red[t >> 6] = esum;
  __syncthreads();
  if (t == 0) { float v = 0.f; for (int i = 0; i < 16; ++i) v += red[i]; red[0] = v; }
  __syncthreads();
  float total = red[0];
  int cnt = fl[0] + fl[1] + fl[2] + fl[3];
  scn[t] = cnt;
  __syncthreads();
  for (int off = 1; off < 1024; off <<= 1) {
    int a = scn[t];
    int b = (t >= off) ? scn[t - off] : 0;
    __syncthreads();
    scn[t] = a + b;
    __syncthreads();
  }
  int p = scn[t] - cnt;
#pragma unroll
  for (int i = 0; i < 4; ++i) {
    if (fl[i]) {
      rows[batch * KSEL + p] = t * 4 + i;
      rwv[batch * KSEL + p]  = ex[i] / total;
      slot[batch * SEQ + t * 4 + i] = batch * KSEL + p;
      ++p;
    }
  }
}

// ---- fused: selected rows -> fp8 Xc (kperm layout); unselected -> out ----
__global__ void gather_copy_kernel(const float* __restrict__ x, const int* __restrict__ sel,
                                   const int* __restrict__ slot,
                                   unsigned char* __restrict__ Xc, float* __restrict__ out) {
  int tokg = blockIdx.x;           // 0..16383
  const float4* src = (const float4*)(x + (size_t)tokg * DIM);
  int t = threadIdx.x;             // 256
  float4 v = src[t];
  if (sel[tokg]) {
    unsigned lo = (unsigned)__builtin_amdgcn_cvt_pk_fp8_f32(v.x, v.y, 0, false);
    unsigned both = (unsigned)__builtin_amdgcn_cvt_pk_fp8_f32(v.z, v.w, (int)lo, true);
    int k = t * 4;
    int pos = (k & ~127) + kperm(k & 127);   // pos % 4 == 0 (k%8 in {0,4})
    *(unsigned*)(Xc + (size_t)slot[tokg] * DIM + pos) = both;
  } else {
    ((float4*)(out + (size_t)tokg * DIM))[t] = v;
  }
}

// ==== MX-FP8 GEMM, reg-staged A: 128x128 tile, BK=128, B-only 16KB LDS ====
// 256 threads = 4 waves (2M x 2N), wave tile 64x64, acc[4][4].
// A fragments are loaded per-lane DIRECTLY from global (contiguous 32B at
// row*K + kt*128 + (lane>>4)*32 -- kperm makes them contiguous; verified
// equivalent to the staged path: stage-XOR and read-XOR cancel, so LDS-B
// (cbs0=even unit, cbs1=odd) and reg-A present identical global byte order,
// which is all the positionally-paired scale-MFMA needs).
// Per-tile LDS traffic halves vs R14 (96->48 KB): stage-B 16KB + read-B 32KB.
// 16 mfma_scale_f32_16x16x128_f8f6f4, scales=1.0 (exact fp8 product).
// W pre-scaled x16 -> epilogue multiplies acc by 1/16.
// EPI=1: H = fp8(gelu(acc/16+b1)) kperm layout;  EPI=2: out = x + rw*(...)
template <int EPI>
__global__ __launch_bounds__(256)
void gemm13(const unsigned char* __restrict__ A, const unsigned char* __restrict__ Bt,
            int M, int N, int K,
            const float* __restrict__ bias,
            unsigned char* __restrict__ Hout,
            const float* __restrict__ x,
            const int* __restrict__ rows,
            const float* __restrict__ rwv,
            float* __restrict__ out) {
  __shared__ __align__(16) unsigned char Bs[128 * 128];   // 16 KB (B only)

  const int t = threadIdx.x;
  const int lane = t & 63;
  const int wid = t >> 6;
  const int wm = wid >> 1;                 // 0..1
  const int wn = wid & 1;                  // 0..1

  // XCD-aware bijective swizzle (gridDim.x % 8 == 0 by construction)
  const int nwg = gridDim.x;
  const int qq = nwg >> 3;
  const int nid = (blockIdx.x & 7) * qq + (blockIdx.x >> 3);
  const int gx = N / 128;
  const int by = nid / gx;
  const int bx = nid - by * gx;
  const int bm0 = by * 128;
  const int bn0 = bx * 128;

  const size_t ldb = (size_t)K;            // row BYTES (fp8)
  const char* Bb = (const char*)Bt + (size_t)bn0 * ldb;
  char* BsB = (char*)Bs;

  // B staging: thread t covers 16B of each 32-row chunk; row = t>>3 (0..31),
  // dest slot = t&7, source slot = (t&7)^(row&7)
  const int srow = t >> 3;
  const size_t stage_off = (size_t)srow * ldb + (size_t)((((t & 7) ^ (srow & 7)) * 16));

  // B fragment b128 offsets within a 128B kperm row (swizzled 16B units);
  // cbs0 always delivers the even global 16B unit, cbs1 the odd one.
  const int cbs0 = ((lane >> 4) * 32     ) ^ ((lane & 7) << 4);
  const int cbs1 = ((lane >> 4) * 32 + 16) ^ ((lane & 7) << 4);

  // A direct-from-global fragment bases: row = bm0 + wm*64 + i*16 + (lane&15),
  // in-row offset = (lane>>4)*32 (32B contiguous, 32B-aligned)
  const char* Ab = (const char*)A;
  const char* arow[4];
#pragma unroll
  for (int i = 0; i < 4; ++i)
    arow[i] = Ab + (size_t)(bm0 + wm * 64 + i * 16 + (lane & 15)) * ldb + (lane >> 4) * 32;

  f32x4_t acc[4][4];
  f32x4_t zero = {0.f, 0.f, 0.f, 0.f};
#pragma unroll
  for (int i = 0; i < 4; ++i)
#pragma unroll
    for (int j = 0; j < 4; ++j) acc[i][j] = zero;

  const int NT = K / 128;

  for (int kt = 0; kt < NT; ++kt) {
    // A fragments: per-lane 32B direct global loads (issue first, max lead)
    i32x8_t am[4];
#pragma unroll
    for (int i = 0; i < 4; ++i)
      am[i] = *(const i32x8_t*)(arow[i] + (size_t)kt * 128);
    // B stage into LDS
    const size_t kb = (size_t)kt * 128 + stage_off;
#pragma unroll
    for (int c = 0; c < 4; ++c)
      GLD16(Bb + kb + (size_t)(c * 32) * ldb, BsB + t * 16 + c * 4096);
    __syncthreads();

    i32x8_t bq[4];
#pragma unroll
    for (int j = 0; j < 4; ++j) {
      const char* bp = BsB + (wn * 64 + j * 16 + (lane & 15)) * 128;
      union { u64x2_t q[2]; i32x8_t v; } u;
      u.q[0] = *(const u64x2_t*)(bp + cbs0);
      u.q[1] = *(const u64x2_t*)(bp + cbs1);
      bq[j] = u.v;
    }
    __builtin_amdgcn_s_setprio(1);
#pragma unroll
    for (int i = 0; i < 4; ++i)
#pragma unroll
      for (int j = 0; j < 4; ++j)
        acc[i][j] = __builtin_amdgcn_mfma_scale_f32_16x16x128_f8f6f4(
            am[i], bq[j], acc[i][j], 0, 0,
            0, 0x7f7f7f7f, 0, 0x7f7f7f7f);   // E8M0 0x7f = 1.0 scales
    __builtin_amdgcn_s_setprio(0);
    __syncthreads();
  }

  // epilogue  (C/D: row = (lane>>4)*4 + qi (M), col = lane&15 (N))
  const int rb = (lane >> 4) * 4;
  const int cc = lane & 15;
#pragma unroll
  for (int i = 0; i < 4; ++i) {
#pragma unroll
    for (int qi = 0; qi < 4; ++qi) {
      int grow = bm0 + wm * 64 + i * 16 + rb + qi;
      if (EPI == 1) {
#pragma unroll
        for (int j = 0; j < 4; ++j) {
          int gcol = bn0 + wn * 64 + j * 16 + cc;
          float v = acc[i][j][qi] * 0.0625f + bias[gcol];
          float cp = 0.7978845608028654f * (v + 0.044715f * v * v * v);
          float g = v / (1.f + __expf(-2.f * cp));   // tanh-approx gelu
          int pos = (gcol & ~127) + kperm(gcol & 127);
          Hout[(size_t)grow * N + pos] = f2fp8(g);
        }
      } else {
        int batch = grow >> 11;
        int tok = rows[grow];
        float rw = rwv[grow];
        size_t obase = ((size_t)(batch * SEQ + tok)) * DIM;
#pragma unroll
        for (int j = 0; j < 4; ++j) {
          int gcol = bn0 + wn * 64 + j * 16 + cc;
          float v = acc[i][j][qi] * 0.0625f + bias[gcol];
          out[obase + gcol] = x[obase + gcol] + rw * v;
        }
      }
    }
  }
}

// ---- aux BCE loss reduction ----
__global__ void aux_kernel(const float* __restrict__ logits, const int* __restrict__ sel,
                           float* __restrict__ out, int out_size) {
  __shared__ float red[16];
  int t = threadIdx.x;
  float sum = 0.f;
  for (int i = t; i < NTOK; i += 1024) {
    float l = logits[i];
    float tgt = sel[i] ? 1.f : 0.f;
    sum += fmaxf(l, 0.f) - l * tgt + log1pf(expf(-fabsf(l)));
  }
#pragma unroll
  for (int off = 32; off > 0; off >>= 1) sum += __shfl_down(sum, off);
  if ((t & 63) == 0) red[t >> 6] = sum;
  __syncthreads();
  if (t == 0) {
    float v = 0.f;
    for (int i = 0; i < 16; ++i) v += red[i];
    out[out_size - 1] = v / (float)NTOK;
  }
}

extern "C" void kernel_launch(void* const* d_in, const int* in_sizes, int n_in,
                              void* d_out, int out_size, void* d_ws, size_t ws_size,
                              hipStream_t stream) {
  const float* x  = (const float*)d_in[0];
  // d_in[1] = attention_mask (unused by reference)
  const float* Wr = (const float*)d_in[2];
  const float* br = (const float*)d_in[3];
  const float* W1 = (const float*)d_in[4];
  const float* b1 = (const float*)d_in[5];
  const float* W2 = (const float*)d_in[6];
  const float* b2 = (const float*)d_in[7];
  float* out = (float*)d_out;

  char* ws = (char*)d_ws;
  float* logits = (float*)(ws);
  float* scores = (float*)(ws + 65536);
  int*   sel    = (int*)(ws + 131072);
  int*   rows   = (int*)(ws + 196608);
  float* rwv    = (float*)(ws + 229376);
  int*   slot   = (int*)(ws + 262144);
  unsigned char* W1t = (unsigned char*)(ws + 327680);                     // 4 MB
  unsigned char* W2t = (unsigned char*)(ws + 327680 + 4194304);           // 4 MB
  unsigned char* Xc  = (unsigned char*)(ws + 327680 + 2 * 4194304);       // 8 MB
  unsigned char* H   = (unsigned char*)(ws + 327680 + 2 * 4194304 + 8388608);  // 32 MB

  prep_kernel<<<12288, 256, 0, stream>>>(W1, W1t, W2, W2t, x, Wr, br, logits, scores);
  rank_kernel<<<NTOK / 16, 256, 0, stream>>>(scores, sel);
  pack_kernel<<<NB, 1024, 0, stream>>>(scores, sel, rows, rwv, slot);
  gather_copy_kernel<<<NTOK, 256, 0, stream>>>(x, sel, slot, Xc, out);
  gemm13<1><<<(MR / 128) * (DFF / 128), 256, 0, stream>>>(
      Xc, W1t, MR, DFF, DIM, b1, H, nullptr, nullptr, nullptr, nullptr);
  gemm13<2><<<(MR / 128) * (DIM / 128), 256, 0, stream>>>(
      H, W2t, MR, DIM, DFF, b2, nullptr, x, rows, rwv, out);
  aux_kernel<<<1, 1024, 0, stream>>>(logits, sel, out, out_size);
}

// Round 16
// 203.021 us; speedup vs baseline: 1.2690x; 1.2690x over previous
//
#include <hip/hip_runtime.h>

#define NB 4
#define SEQ 4096
#define DIM 1024
#define DFF 4096
#define KSEL 2048
#define NTOK (NB * SEQ)   // 16384
#define MR (NB * KSEL)    // 8192

typedef float f32x4_t __attribute__((ext_vector_type(4)));
typedef unsigned long u64_t;
typedef unsigned long u64x2_t __attribute__((ext_vector_type(2)));
typedef int i32x8_t __attribute__((ext_vector_type(8)));

// HW f32->fp8 e4m3 (OCP, RNE, saturating)
__device__ __forceinline__ unsigned char f2fp8(float f) {
  return (unsigned char)(__builtin_amdgcn_cvt_pk_fp8_f32(f, f, 0, false) & 0xff);
}

// fragment-friendly byte permutation within a 128B K-block:
// k = kk*32 + slot*8 + b  ->  pos = slot*32 + kk*8 + b
__device__ __forceinline__ int kperm(int kb) {
  return ((kb >> 3) & 3) * 32 + (kb >> 5) * 8 + (kb & 7);
}

#define GLD16(g, l) __builtin_amdgcn_global_load_lds( \
    (const __attribute__((address_space(1))) void*)(g), \
    (__attribute__((address_space(3))) void*)(l), 16, 0, 0)

// ---- fused prep: W1/W2 transpose+cast (blocks 0..8191) + router GEMV
//      (blocks 8192..12287) -- independent work, one launch ----
__global__ void prep_kernel(const float* __restrict__ W1, unsigned char* __restrict__ W1t,
                            const float* __restrict__ W2, unsigned char* __restrict__ W2t,
                            const float* __restrict__ x, const float* __restrict__ Wr,
                            const float* __restrict__ br,
                            float* __restrict__ logits, float* __restrict__ scores) {
  __shared__ float tl[32][33];
  int bid = blockIdx.x;
  if (bid < 8192) {
    const float* W; unsigned char* Wt; int R, C, bx, by;
    if (bid < 4096) { W = W1; Wt = W1t; R = DIM; C = DFF; bx = bid & 127; by = bid >> 7; }
    else { bid -= 4096; W = W2; Wt = W2t; R = DFF; C = DIM; bx = bid & 31; by = bid >> 5; }
    int c0 = bx * 32;
    int r0 = by * 32;
    int tx = threadIdx.x & 31, ty = threadIdx.x >> 5;
#pragma unroll
    for (int i = 0; i < 4; ++i)
      tl[ty + i * 8][tx] = W[(size_t)(r0 + ty + i * 8) * C + c0 + tx];
    __syncthreads();
    int k = r0 + tx;
    int pos = (k & ~127) + kperm(k & 127);
#pragma unroll
    for (int i = 0; i < 4; ++i)
      Wt[(size_t)(c0 + ty + i * 8) * R + pos] = f2fp8(16.f * tl[tx][ty + i * 8]);
  } else {
    int lane = threadIdx.x & 63;
    int wid  = threadIdx.x >> 6;
    int row  = (bid - 8192) * 4 + wid;        // 0..16383
    const float4* xr = (const float4*)(x + (size_t)row * DIM);
    const float4* w4 = (const float4*)Wr;
    float sum = 0.f;
#pragma unroll
    for (int i = 0; i < 4; ++i) {
      float4 a = xr[lane + i * 64];
      float4 w = w4[lane + i * 64];
      sum += a.x * w.x + a.y * w.y + a.z * w.z + a.w * w.w;
    }
#pragma unroll
    for (int off = 32; off > 0; off >>= 1) sum += __shfl_down(sum, off);
    if (lane == 0) {
      float l = sum + br[0];
      logits[row] = l;
      scores[row] = 1.f / (1.f + expf(-l));
    }
  }
}

// ---- exact top-k via rank counting (matches jax.lax.top_k tie-break) ----
__global__ void rank_kernel(const float* __restrict__ scores, int* __restrict__ sel) {
  __shared__ float s_sc[SEQ];
  int batch = blockIdx.x >> 8;        // 256 blocks per batch
  int chunk = blockIdx.x & 255;
  int t = threadIdx.x;                // 256
  const float4* sb4 = (const float4*)(scores + batch * SEQ);
  float4* ls4 = (float4*)s_sc;
#pragma unroll
  for (int i = 0; i < 4; ++i) ls4[t + i * 256] = sb4[t + i * 256];
  __syncthreads();
  int tok = chunk * 16 + (t >> 4);    // token this thread contributes to
  int sg  = t & 15;                   // score segment 0..15 (256 scores each)
  float s = s_sc[tok];
  const float4* seg = ls4 + sg * 64;
  int jbase = sg * 256;
  int rank = 0;
#pragma unroll 4
  for (int j4 = 0; j4 < 64; ++j4) {
    float4 v = seg[j4];
    int j = jbase + j4 * 4;
    rank += (v.x > s || (v.x == s && j     < tok)) ? 1 : 0;
    rank += (v.y > s || (v.y == s && j + 1 < tok)) ? 1 : 0;
    rank += (v.z > s || (v.z == s && j + 2 < tok)) ? 1 : 0;
    rank += (v.w > s || (v.w == s && j + 3 < tok)) ? 1 : 0;
  }
#pragma unroll
  for (int off = 8; off > 0; off >>= 1) rank += __shfl_down(rank, off, 16);
  if (sg == 0) sel[batch * SEQ + tok] = (rank < KSEL) ? 1 : 0;
}

// ---- per-batch: softmax over selected scores + prefix-sum compaction ----
__global__ void pack_kernel(const float* __restrict__ scores, const int* __restrict__ sel,
                            int* __restrict__ rows, float* __restrict__ rwv,
                            int* __restrict__ slot) {
  __shared__ float red[16];
  __shared__ int scn[1024];
  int batch = blockIdx.x;
  int t = threadIdx.x;
  const float* sb = scores + batch * SEQ;
  const int* fb = sel + batch * SEQ;
  float sc[4]; int fl[4];
#pragma unroll
  for (int i = 0; i < 4; ++i) { sc[i] = sb[t * 4 + i]; fl[i] = fb[t * 4 + i]; }
  float m = fmaxf(fmaxf(sc[0], sc[1]), fmaxf(sc[2], sc[3]));
#pragma unroll
  for (int off = 32; off > 0; off >>= 1) m = fmaxf(m, __shfl_down(m, off));
  if ((t & 63) == 0) red[t >> 6] = m;
  __syncthreads();
  if (t == 0) { float v = red[0]; for (int i = 1; i < 16; ++i) v = fmaxf(v, red[i]); red[0] = v; }
  __syncthreads();
  m = red[0];
  __syncthreads();
  float ex[4]; float esum = 0.f;
#pragma unroll
  for (int i = 0; i < 4; ++i) { ex[i] = expf(sc[i] - m); if (fl[i]) esum += ex[i]; }
#pragma unroll
  for (int off = 32; off > 0; off >>= 1) esum += __shfl_down(esum, off);
  if ((t & 63) == 0) red[t >> 6] = esum;
  __syncthreads();
  if (t == 0) { float v = 0.f; for (int i = 0; i < 16; ++i) v += red[i]; red[0] = v; }
  __syncthreads();
  float total = red[0];
  int cnt = fl[0] + fl[1] + fl[2] + fl[3];
  scn[t] = cnt;
  __syncthreads();
  for (int off = 1; off < 1024; off <<= 1) {
    int a = scn[t];
    int b = (t >= off) ? scn[t - off] : 0;
    __syncthreads();
    scn[t] = a + b;
    __syncthreads();
  }
  int p = scn[t] - cnt;
#pragma unroll
  for (int i = 0; i < 4; ++i) {
    if (fl[i]) {
      rows[batch * KSEL + p] = t * 4 + i;
      rwv[batch * KSEL + p]  = ex[i] / total;
      slot[batch * SEQ + t * 4 + i] = batch * KSEL + p;
      ++p;
    }
  }
}

// ---- fused: selected rows -> fp8 Xc (PANEL-major kperm layout);
//      unselected rows -> out (= x) ----
// Xc layout: [panel=mrow/128][kt=k/128][slot=pos/32][row=mrow%128][b=pos%32]
__global__ void gather_copy_kernel(const float* __restrict__ x, const int* __restrict__ sel,
                                   const int* __restrict__ slot,
                                   unsigned char* __restrict__ Xc, float* __restrict__ out) {
  int tokg = blockIdx.x;           // 0..16383
  const float4* src = (const float4*)(x + (size_t)tokg * DIM);
  int t = threadIdx.x;             // 256
  float4 v = src[t];
  if (sel[tokg]) {
    unsigned lo = (unsigned)__builtin_amdgcn_cvt_pk_fp8_f32(v.x, v.y, 0, false);
    unsigned both = (unsigned)__builtin_amdgcn_cvt_pk_fp8_f32(v.z, v.w, (int)lo, true);
    int mrow = slot[tokg];
    int panel = mrow >> 7, rowp = mrow & 127;
    int k = t * 4;
    int pos = kperm(k & 127);      // pos % 4 == 0
    size_t addr = (size_t)panel * (128 * DIM) + (size_t)(k >> 7) * 16384
                + (size_t)(pos >> 5) * 4096 + (size_t)rowp * 32 + (pos & 31);
    *(unsigned*)(Xc + addr) = both;
  } else {
    ((float4*)(out + (size_t)tokg * DIM))[t] = v;
  }
}

// ==== MX-FP8 GEMM: panel-major COALESCED reg-A + LDS-staged B ====
// 128x128 tile, BK=128, 256 threads = 4 waves (2M x 2N), wave tile 64x64.
// A is panel-major: lane's 32B fragment sits at panel + kt*16384 +
// slot*4096 + row*32 -> lanes 0..15 read 512B CONTIGUOUS (fixes R15's
// scatter). No A staging, no A LDS reads: per-tile LDS traffic 96->48 KB.
// B: row-major kperm + XOR-swizzle stage (byte-identical to R14, verified).
// 16 mfma_scale_f32_16x16x128_f8f6f4, scales=1.0 (exact fp8 product).
// W pre-scaled x16 -> epilogue multiplies acc by 1/16.
// EPI=1: H = fp8(gelu(acc/16+b1)) PANEL-major;  EPI=2: out = x + rw*(...)
template <int EPI>
__global__ __launch_bounds__(256)
void gemm14(const unsigned char* __restrict__ A, const unsigned char* __restrict__ Bt,
            int M, int N, int K,
            const float* __restrict__ bias,
            unsigned char* __restrict__ Hout,
            const float* __restrict__ x,
            const int* __restrict__ rows,
            const float* __restrict__ rwv,
            float* __restrict__ out) {
  __shared__ __align__(16) unsigned char Bs[128 * 128];   // 16 KB (B only)

  const int t = threadIdx.x;
  const int lane = t & 63;
  const int wid = t >> 6;
  const int wm = wid >> 1;                 // 0..1
  const int wn = wid & 1;                  // 0..1

  // XCD-aware bijective swizzle (gridDim.x % 8 == 0 by construction)
  const int nwg = gridDim.x;
  const int qq = nwg >> 3;
  const int nid = (blockIdx.x & 7) * qq + (blockIdx.x >> 3);
  const int gx = N / 128;
  const int by = nid / gx;
  const int bx = nid - by * gx;
  const int bm0 = by * 128;
  const int bn0 = bx * 128;

  const size_t ldb = (size_t)K;            // row BYTES (fp8)
  const char* Bb = (const char*)Bt + (size_t)bn0 * ldb;
  char* BsB = (char*)Bs;

  // B staging: thread t covers 16B of each 32-row chunk; row = t>>3 (0..31),
  // dest slot = t&7, source slot = (t&7)^(row&7)
  const int srow = t >> 3;
  const size_t stage_off = (size_t)srow * ldb + (size_t)((((t & 7) ^ (srow & 7)) * 16));

  // B fragment b128 offsets within a 128B kperm row (swizzled 16B units)
  const int cbs0 = ((lane >> 4) * 32     ) ^ ((lane & 7) << 4);
  const int cbs1 = ((lane >> 4) * 32 + 16) ^ ((lane & 7) << 4);

  // A panel-major fragment bases: panel = by (bm0 = by*128);
  // addr = panel*128*K + kt*16384 + (lane>>4)*4096 + rowp*32
  const char* Ap = (const char*)A + (size_t)by * 128 * (size_t)K + (size_t)(lane >> 4) * 4096;
  const char* arow[4];
#pragma unroll
  for (int i = 0; i < 4; ++i)
    arow[i] = Ap + (size_t)(wm * 64 + i * 16 + (lane & 15)) * 32;

  f32x4_t acc[4][4];
  f32x4_t zero = {0.f, 0.f, 0.f, 0.f};
#pragma unroll
  for (int i = 0; i < 4; ++i)
#pragma unroll
    for (int j = 0; j < 4; ++j) acc[i][j] = zero;

  const int NT = K / 128;

  for (int kt = 0; kt < NT; ++kt) {
    // A fragments: coalesced 32B/lane direct global loads (512B per 16 lanes)
    i32x8_t am[4];
#pragma unroll
    for (int i = 0; i < 4; ++i)
      am[i] = *(const i32x8_t*)(arow[i] + (size_t)kt * 16384);
    // B stage into LDS
    const size_t kb = (size_t)kt * 128 + stage_off;
#pragma unroll
    for (int c = 0; c < 4; ++c)
      GLD16(Bb + kb + (size_t)(c * 32) * ldb, BsB + t * 16 + c * 4096);
    __syncthreads();

    i32x8_t bq[4];
#pragma unroll
    for (int j = 0; j < 4; ++j) {
      const char* bp = BsB + (wn * 64 + j * 16 + (lane & 15)) * 128;
      union { u64x2_t q[2]; i32x8_t v; } u;
      u.q[0] = *(const u64x2_t*)(bp + cbs0);
      u.q[1] = *(const u64x2_t*)(bp + cbs1);
      bq[j] = u.v;
    }
    __builtin_amdgcn_s_setprio(1);
#pragma unroll
    for (int i = 0; i < 4; ++i)
#pragma unroll
      for (int j = 0; j < 4; ++j)
        acc[i][j] = __builtin_amdgcn_mfma_scale_f32_16x16x128_f8f6f4(
            am[i], bq[j], acc[i][j], 0, 0,
            0, 0x7f7f7f7f, 0, 0x7f7f7f7f);   // E8M0 0x7f = 1.0 scales
    __builtin_amdgcn_s_setprio(0);
    __syncthreads();
  }

  // epilogue  (C/D: row = (lane>>4)*4 + qi (M), col = lane&15 (N))
  const int rb = (lane >> 4) * 4;
  const int cc = lane & 15;
#pragma unroll
  for (int i = 0; i < 4; ++i) {
#pragma unroll
    for (int qi = 0; qi < 4; ++qi) {
      int grow = bm0 + wm * 64 + i * 16 + rb + qi;
      if (EPI == 1) {
        int panel = grow >> 7, rowp = grow & 127;
#pragma unroll
        for (int j = 0; j < 4; ++j) {
          int gcol = bn0 + wn * 64 + j * 16 + cc;
          float v = acc[i][j][qi] * 0.0625f + bias[gcol];
          float cp = 0.7978845608028654f * (v + 0.044715f * v * v * v);
          float g = v / (1.f + __expf(-2.f * cp));   // tanh-approx gelu
          int pos = kperm(gcol & 127);
          size_t addr = (size_t)panel * (128 * DFF) + (size_t)(gcol >> 7) * 16384
                      + (size_t)(pos >> 5) * 4096 + (size_t)rowp * 32 + (pos & 31);
          Hout[addr] = f2fp8(g);
        }
      } else {
        int batch = grow >> 11;
        int tok = rows[grow];
        float rw = rwv[grow];
        size_t obase = ((size_t)(batch * SEQ + tok)) * DIM;
#pragma unroll
        for (int j = 0; j < 4; ++j) {
          int gcol = bn0 + wn * 64 + j * 16 + cc;
          float v = acc[i][j][qi] * 0.0625f + bias[gcol];
          out[obase + gcol] = x[obase + gcol] + rw * v;
        }
      }
    }
  }
}

// ---- aux BCE loss reduction ----
__global__ void aux_kernel(const float* __restrict__ logits, const int* __restrict__ sel,
                           float* __restrict__ out, int out_size) {
  __shared__ float red[16];
  int t = threadIdx.x;
  float sum = 0.f;
  for (int i = t; i < NTOK; i += 1024) {
    float l = logits[i];
    float tgt = sel[i] ? 1.f : 0.f;
    sum += fmaxf(l, 0.f) - l * tgt + log1pf(expf(-fabsf(l)));
  }
#pragma unroll
  for (int off = 32; off > 0; off >>= 1) sum += __shfl_down(sum, off);
  if ((t & 63) == 0) red[t >> 6] = sum;
  __syncthreads();
  if (t == 0) {
    float v = 0.f;
    for (int i = 0; i < 16; ++i) v += red[i];
    out[out_size - 1] = v / (float)NTOK;
  }
}

extern "C" void kernel_launch(void* const* d_in, const int* in_sizes, int n_in,
                              void* d_out, int out_size, void* d_ws, size_t ws_size,
                              hipStream_t stream) {
  const float* x  = (const float*)d_in[0];
  // d_in[1] = attention_mask (unused by reference)
  const float* Wr = (const float*)d_in[2];
  const float* br = (const float*)d_in[3];
  const float* W1 = (const float*)d_in[4];
  const float* b1 = (const float*)d_in[5];
  const float* W2 = (const float*)d_in[6];
  const float* b2 = (const float*)d_in[7];
  float* out = (float*)d_out;

  char* ws = (char*)d_ws;
  float* logits = (float*)(ws);
  float* scores = (float*)(ws + 65536);
  int*   sel    = (int*)(ws + 131072);
  int*   rows   = (int*)(ws + 196608);
  float* rwv    = (float*)(ws + 229376);
  int*   slot   = (int*)(ws + 262144);
  unsigned char* W1t = (unsigned char*)(ws + 327680);                     // 4 MB
  unsigned char* W2t = (unsigned char*)(ws + 327680 + 4194304);           // 4 MB
  unsigned char* Xc  = (unsigned char*)(ws + 327680 + 2 * 4194304);       // 8 MB
  unsigned char* H   = (unsigned char*)(ws + 327680 + 2 * 4194304 + 8388608);  // 32 MB

  prep_kernel<<<12288, 256, 0, stream>>>(W1, W1t, W2, W2t, x, Wr, br, logits, scores);
  rank_kernel<<<NTOK / 16, 256, 0, stream>>>(scores, sel);
  pack_kernel<<<NB, 1024, 0, stream>>>(scores, sel, rows, rwv, slot);
  gather_copy_kernel<<<NTOK, 256, 0, stream>>>(x, sel, slot, Xc, out);
  gemm14<1><<<(MR / 128) * (DFF / 128), 256, 0, stream>>>(
      Xc, W1t, MR, DFF, DIM, b1, H, nullptr, nullptr, nullptr, nullptr);
  gemm14<2><<<(MR / 128) * (DIM / 128), 256, 0, stream>>>(
      H, W2t, MR, DIM, DFF, b2, nullptr, x, rows, rwv, out);
  aux_kernel<<<1, 1024, 0, stream>>>(logits, sel, out, out_size);
}

// Round 17
// 200.751 us; speedup vs baseline: 1.2834x; 1.0113x over previous
//
#include <hip/hip_runtime.h>

#define NB 4
#define SEQ 4096
#define DIM 1024
#define DFF 4096
#define KSEL 2048
#define NTOK (NB * SEQ)   // 16384
#define MR (NB * KSEL)    // 8192

typedef float f32x4_t __attribute__((ext_vector_type(4)));
typedef unsigned long u64_t;
typedef unsigned long u64x2_t __attribute__((ext_vector_type(2)));
typedef int i32x8_t __attribute__((ext_vector_type(8)));

// HW f32->fp8 e4m3 (OCP, RNE, saturating)
__device__ __forceinline__ unsigned char f2fp8(float f) {
  return (unsigned char)(__builtin_amdgcn_cvt_pk_fp8_f32(f, f, 0, false) & 0xff);
}

// fragment-friendly byte permutation within a 128B K-block:
// k = kk*32 + slot*8 + b  ->  pos = slot*32 + kk*8 + b
__device__ __forceinline__ int kperm(int kb) {
  return ((kb >> 3) & 3) * 32 + (kb >> 5) * 8 + (kb & 7);
}

#define GLD16(g, l) __builtin_amdgcn_global_load_lds( \
    (const __attribute__((address_space(1))) void*)(g), \
    (__attribute__((address_space(3))) void*)(l), 16, 0, 0)

// ---- fused prep: W1/W2 transpose+cast (blocks 0..8191) + router GEMV
//      with full x->out copy (blocks 8192..12287) ----
__global__ void prep_kernel(const float* __restrict__ W1, unsigned char* __restrict__ W1t,
                            const float* __restrict__ W2, unsigned char* __restrict__ W2t,
                            const float* __restrict__ x, const float* __restrict__ Wr,
                            const float* __restrict__ br,
                            float* __restrict__ logits, float* __restrict__ scores,
                            float* __restrict__ out) {
  __shared__ float tl[32][33];
  int bid = blockIdx.x;
  if (bid < 8192) {
    const float* W; unsigned char* Wt; int R, C, bx, by;
    if (bid < 4096) { W = W1; Wt = W1t; R = DIM; C = DFF; bx = bid & 127; by = bid >> 7; }
    else { bid -= 4096; W = W2; Wt = W2t; R = DFF; C = DIM; bx = bid & 31; by = bid >> 5; }
    int c0 = bx * 32;
    int r0 = by * 32;
    int tx = threadIdx.x & 31, ty = threadIdx.x >> 5;
#pragma unroll
    for (int i = 0; i < 4; ++i)
      tl[ty + i * 8][tx] = W[(size_t)(r0 + ty + i * 8) * C + c0 + tx];
    __syncthreads();
    int k = r0 + tx;
    int pos = (k & ~127) + kperm(k & 127);
#pragma unroll
    for (int i = 0; i < 4; ++i)
      Wt[(size_t)(c0 + ty + i * 8) * R + pos] = f2fp8(16.f * tl[tx][ty + i * 8]);
  } else {
    int lane = threadIdx.x & 63;
    int wid  = threadIdx.x >> 6;
    int row  = (bid - 8192) * 4 + wid;        // 0..16383
    const float4* xr = (const float4*)(x + (size_t)row * DIM);
    float4* orow = (float4*)(out + (size_t)row * DIM);
    const float4* w4 = (const float4*)Wr;
    float sum = 0.f;
#pragma unroll
    for (int i = 0; i < 4; ++i) {
      float4 a = xr[lane + i * 64];
      float4 w = w4[lane + i * 64];
      orow[lane + i * 64] = a;                // out = x (selected rows fixed later)
      sum += a.x * w.x + a.y * w.y + a.z * w.z + a.w * w.w;
    }
#pragma unroll
    for (int off = 32; off > 0; off >>= 1) sum += __shfl_down(sum, off);
    if (lane == 0) {
      float l = sum + br[0];
      logits[row] = l;
      scores[row] = 1.f / (1.f + expf(-l));
    }
  }
}

// ---- exact top-k via rank counting (matches jax.lax.top_k tie-break) ----
__global__ void rank_kernel(const float* __restrict__ scores, int* __restrict__ sel) {
  __shared__ float s_sc[SEQ];
  int batch = blockIdx.x >> 8;        // 256 blocks per batch
  int chunk = blockIdx.x & 255;
  int t = threadIdx.x;                // 256
  const float4* sb4 = (const float4*)(scores + batch * SEQ);
  float4* ls4 = (float4*)s_sc;
#pragma unroll
  for (int i = 0; i < 4; ++i) ls4[t + i * 256] = sb4[t + i * 256];
  __syncthreads();
  int tok = chunk * 16 + (t >> 4);    // token this thread contributes to
  int sg  = t & 15;                   // score segment 0..15 (256 scores each)
  float s = s_sc[tok];
  const float4* seg = ls4 + sg * 64;
  int jbase = sg * 256;
  int rank = 0;
#pragma unroll 4
  for (int j4 = 0; j4 < 64; ++j4) {
    float4 v = seg[j4];
    int j = jbase + j4 * 4;
    rank += (v.x > s || (v.x == s && j     < tok)) ? 1 : 0;
    rank += (v.y > s || (v.y == s && j + 1 < tok)) ? 1 : 0;
    rank += (v.z > s || (v.z == s && j + 2 < tok)) ? 1 : 0;
    rank += (v.w > s || (v.w == s && j + 3 < tok)) ? 1 : 0;
  }
#pragma unroll
  for (int off = 8; off > 0; off >>= 1) rank += __shfl_down(rank, off, 16);
  if (sg == 0) sel[batch * SEQ + tok] = (rank < KSEL) ? 1 : 0;
}

// ---- per-batch: softmax over selected scores + prefix-sum compaction ----
__global__ void pack_kernel(const float* __restrict__ scores, const int* __restrict__ sel,
                            int* __restrict__ rows, float* __restrict__ rwv) {
  __shared__ float red[16];
  __shared__ int scn[1024];
  int batch = blockIdx.x;
  int t = threadIdx.x;
  const float* sb = scores + batch * SEQ;
  const int* fb = sel + batch * SEQ;
  float sc[4]; int fl[4];
#pragma unroll
  for (int i = 0; i < 4; ++i) { sc[i] = sb[t * 4 + i]; fl[i] = fb[t * 4 + i]; }
  float m = fmaxf(fmaxf(sc[0], sc[1]), fmaxf(sc[2], sc[3]));
#pragma unroll
  for (int off = 32; off > 0; off >>= 1) m = fmaxf(m, __shfl_down(m, off));
  if ((t & 63) == 0) red[t >> 6] = m;
  __syncthreads();
  if (t == 0) { float v = red[0]; for (int i = 1; i < 16; ++i) v = fmaxf(v, red[i]); red[0] = v; }
  __syncthreads();
  m = red[0];
  __syncthreads();
  float ex[4]; float esum = 0.f;
#pragma unroll
  for (int i = 0; i < 4; ++i) { ex[i] = expf(sc[i] - m); if (fl[i]) esum += ex[i]; }
#pragma unroll
  for (int off = 32; off > 0; off >>= 1) esum += __shfl_down(esum, off);
  if ((t & 63) == 0) red[t >> 6] = esum;
  __syncthreads();
  if (t == 0) { float v = 0.f; for (int i = 0; i < 16; ++i) v += red[i]; red[0] = v; }
  __syncthreads();
  float total = red[0];
  int cnt = fl[0] + fl[1] + fl[2] + fl[3];
  scn[t] = cnt;
  __syncthreads();
  for (int off = 1; off < 1024; off <<= 1) {
    int a = scn[t];
    int b = (t >= off) ? scn[t - off] : 0;
    __syncthreads();
    scn[t] = a + b;
    __syncthreads();
  }
  int p = scn[t] - cnt;
#pragma unroll
  for (int i = 0; i < 4; ++i) {
    if (fl[i]) {
      rows[batch * KSEL + p] = t * 4 + i;
      rwv[batch * KSEL + p]  = ex[i] / total;
      ++p;
    }
  }
}

// ---- gather selected rows -> fp8 Xc (PANEL-major kperm layout) ----
// Xc layout: [panel=mrow/128][kt=k/128][slot=pos/32][row=mrow%128][b=pos%32]
__global__ void gather_kernel(const float* __restrict__ x, const int* __restrict__ rows,
                              unsigned char* __restrict__ Xc) {
  int mrow = blockIdx.x;           // 0..8191
  int batch = mrow >> 11;
  int tok = rows[mrow];
  const float4* src = (const float4*)(x + ((size_t)(batch * SEQ + tok)) * DIM);
  int t = threadIdx.x;             // 256
  float4 v = src[t];
  unsigned lo = (unsigned)__builtin_amdgcn_cvt_pk_fp8_f32(v.x, v.y, 0, false);
  unsigned both = (unsigned)__builtin_amdgcn_cvt_pk_fp8_f32(v.z, v.w, (int)lo, true);
  int panel = mrow >> 7, rowp = mrow & 127;
  int k = t * 4;
  int pos = kperm(k & 127);        // pos % 4 == 0
  size_t addr = (size_t)panel * (128 * DIM) + (size_t)(k >> 7) * 16384
              + (size_t)(pos >> 5) * 4096 + (size_t)rowp * 32 + (pos & 31);
  *(unsigned*)(Xc + addr) = both;
}

// ==== MX-FP8 GEMM: panel-major reg-A + dbuf LDS-B, depth-1 counted prefetch ====
// 128x128 tile, BK=128, 256 threads = 4 waves (2M x 2N), wave tile 64x64.
// Per tile: issue A(t+1) reg-loads + B-stage(t+1) [8 VMEM ops] ->
// s_waitcnt vmcnt(8) [tile t's 8 ops complete, t+1 stays in flight] ->
// raw s_barrier -> compute(t) -> s_barrier. Never drains to 0 till the end
// (T3 minimal 2-phase: counted vmcnt replaces __syncthreads' vmcnt(0) drain).
// A panel-major: lanes 0..15 read 512B contiguous (R16-verified).
// B row-major kperm + XOR-swizzle stage (R14-verified, ~2-way conflicts).
// 16 mfma_scale_f32_16x16x128_f8f6f4, scales=1.0 (exact fp8 product).
// W pre-scaled x16 -> epilogue multiplies acc by 1/16.
// EPI=1: H = fp8(gelu(acc/16+b1)) PANEL-major;  EPI=2: out = x + rw*(...)
template <int EPI>
__global__ __launch_bounds__(256)
void gemm15(const unsigned char* __restrict__ A, const unsigned char* __restrict__ Bt,
            int M, int N, int K,
            const float* __restrict__ bias,
            unsigned char* __restrict__ Hout,
            const float* __restrict__ x,
            const int* __restrict__ rows,
            const float* __restrict__ rwv,
            float* __restrict__ out) {
  __shared__ __align__(16) unsigned char Bs[2][128 * 128];   // 32 KB

  const int t = threadIdx.x;
  const int lane = t & 63;
  const int wid = t >> 6;
  const int wm = wid >> 1;                 // 0..1
  const int wn = wid & 1;                  // 0..1

  // XCD-aware bijective swizzle (gridDim.x % 8 == 0 by construction)
  const int nwg = gridDim.x;
  const int qq = nwg >> 3;
  const int nid = (blockIdx.x & 7) * qq + (blockIdx.x >> 3);
  const int gx = N / 128;
  const int by = nid / gx;
  const int bx = nid - by * gx;
  const int bm0 = by * 128;
  const int bn0 = bx * 128;

  const size_t ldb = (size_t)K;            // row BYTES (fp8)
  const char* Bb = (const char*)Bt + (size_t)bn0 * ldb;

  // B staging: thread t covers 16B of each 32-row chunk; row = t>>3 (0..31),
  // dest slot = t&7, source slot = (t&7)^(row&7)
  const int srow = t >> 3;
  const size_t stage_off = (size_t)srow * ldb + (size_t)((((t & 7) ^ (srow & 7)) * 16));

  // B fragment b128 offsets within a 128B kperm row (swizzled 16B units)
  const int cbs0 = ((lane >> 4) * 32     ) ^ ((lane & 7) << 4);
  const int cbs1 = ((lane >> 4) * 32 + 16) ^ ((lane & 7) << 4);

  // A panel-major fragment bases (panel = by)
  const char* Ap = (const char*)A + (size_t)by * 128 * (size_t)K + (size_t)(lane >> 4) * 4096;
  const char* arow[4];
#pragma unroll
  for (int i = 0; i < 4; ++i)
    arow[i] = Ap + (size_t)(wm * 64 + i * 16 + (lane & 15)) * 32;

  f32x4_t acc[4][4];
  f32x4_t zero = {0.f, 0.f, 0.f, 0.f};
#pragma unroll
  for (int i = 0; i < 4; ++i)
#pragma unroll
    for (int j = 0; j < 4; ++j) acc[i][j] = zero;

  const int NT = K / 128;                  // 8 or 32 (even)

  i32x8_t amA[4], amB[4];

  auto loadA = [&](i32x8_t* am, int kt) {
#pragma unroll
    for (int i = 0; i < 4; ++i)
      am[i] = *(const i32x8_t*)(arow[i] + (size_t)kt * 16384);
  };
  auto stageB = [&](int buf, int kt) {
    const size_t kb = (size_t)kt * 128 + stage_off;
    char* dst = (char*)Bs[buf] + t * 16;
#pragma unroll
    for (int c = 0; c < 4; ++c)
      GLD16(Bb + kb + (size_t)(c * 32) * ldb, dst + c * 4096);
  };
  auto compute = [&](const i32x8_t* am, int buf) {
    i32x8_t bq[4];
#pragma unroll
    for (int j = 0; j < 4; ++j) {
      const char* bp = (const char*)Bs[buf] + (wn * 64 + j * 16 + (lane & 15)) * 128;
      union { u64x2_t q[2]; i32x8_t v; } u;
      u.q[0] = *(const u64x2_t*)(bp + cbs0);
      u.q[1] = *(const u64x2_t*)(bp + cbs1);
      bq[j] = u.v;
    }
    __builtin_amdgcn_s_setprio(1);
#pragma unroll
    for (int i = 0; i < 4; ++i)
#pragma unroll
      for (int j = 0; j < 4; ++j)
        acc[i][j] = __builtin_amdgcn_mfma_scale_f32_16x16x128_f8f6f4(
            am[i], bq[j], acc[i][j], 0, 0,
            0, 0x7f7f7f7f, 0, 0x7f7f7f7f);   // E8M0 0x7f = 1.0 scales
    __builtin_amdgcn_s_setprio(0);
  };

  // prologue: tile 0 in flight
  loadA(amA, 0);
  stageB(0, 0);

  for (int kt = 0; kt < NT; kt += 2) {
    // ---- phase 1: compute kt (amA, buf0), prefetch kt+1 ----
    loadA(amB, kt + 1);                    // NT even => kt+1 < NT always
    stageB(1, kt + 1);
    asm volatile("s_waitcnt vmcnt(8)" ::: "memory");
    __builtin_amdgcn_s_barrier();
    __builtin_amdgcn_sched_barrier(0);
    compute(amA, 0);
    __builtin_amdgcn_s_barrier();
    // ---- phase 2: compute kt+1 (amB, buf1), prefetch kt+2 ----
    if (kt + 2 < NT) {
      loadA(amA, kt + 2);
      stageB(0, kt + 2);
      asm volatile("s_waitcnt vmcnt(8)" ::: "memory");
    } else {
      asm volatile("s_waitcnt vmcnt(0)" ::: "memory");
    }
    __builtin_amdgcn_s_barrier();
    __builtin_amdgcn_sched_barrier(0);
    compute(amB, 1);
    __builtin_amdgcn_s_barrier();
  }

  // epilogue  (C/D: row = (lane>>4)*4 + qi (M), col = lane&15 (N))
  const int rb = (lane >> 4) * 4;
  const int cc = lane & 15;
#pragma unroll
  for (int i = 0; i < 4; ++i) {
#pragma unroll
    for (int qi = 0; qi < 4; ++qi) {
      int grow = bm0 + wm * 64 + i * 16 + rb + qi;
      if (EPI == 1) {
        int panel = grow >> 7, rowp = grow & 127;
#pragma unroll
        for (int j = 0; j < 4; ++j) {
          int gcol = bn0 + wn * 64 + j * 16 + cc;
          float v = acc[i][j][qi] * 0.0625f + bias[gcol];
          float cp = 0.7978845608028654f * (v + 0.044715f * v * v * v);
          float g = v / (1.f + __expf(-2.f * cp));   // tanh-approx gelu
          int pos = kperm(gcol & 127);
          size_t addr = (size_t)panel * (128 * DFF) + (size_t)(gcol >> 7) * 16384
                      + (size_t)(pos >> 5) * 4096 + (size_t)rowp * 32 + (pos & 31);
          Hout[addr] = f2fp8(g);
        }
      } else {
        int batch = grow >> 11;
        int tok = rows[grow];
        float rw = rwv[grow];
        size_t obase = ((size_t)(batch * SEQ + tok)) * DIM;
#pragma unroll
        for (int j = 0; j < 4; ++j) {
          int gcol = bn0 + wn * 64 + j * 16 + cc;
          float v = acc[i][j][qi] * 0.0625f + bias[gcol];
          out[obase + gcol] = x[obase + gcol] + rw * v;
        }
      }
    }
  }
}

// ---- aux BCE loss reduction ----
__global__ void aux_kernel(const float* __restrict__ logits, const int* __restrict__ sel,
                           float* __restrict__ out, int out_size) {
  __shared__ float red[16];
  int t = threadIdx.x;
  float sum = 0.f;
  for (int i = t; i < NTOK; i += 1024) {
    float l = logits[i];
    float tgt = sel[i] ? 1.f : 0.f;
    sum += fmaxf(l, 0.f) - l * tgt + log1pf(expf(-fabsf(l)));
  }
#pragma unroll
  for (int off = 32; off > 0; off >>= 1) sum += __shfl_down(sum, off);
  if ((t & 63) == 0) red[t >> 6] = sum;
  __syncthreads();
  if (t == 0) {
    float v = 0.f;
    for (int i = 0; i < 16; ++i) v += red[i];
    out[out_size - 1] = v / (float)NTOK;
  }
}

extern "C" void kernel_launch(void* const* d_in, const int* in_sizes, int n_in,
                              void* d_out, int out_size, void* d_ws, size_t ws_size,
                              hipStream_t stream) {
  const float* x  = (const float*)d_in[0];
  // d_in[1] = attention_mask (unused by reference)
  const float* Wr = (const float*)d_in[2];
  const float* br = (const float*)d_in[3];
  const float* W1 = (const float*)d_in[4];
  const float* b1 = (const float*)d_in[5];
  const float* W2 = (const float*)d_in[6];
  const float* b2 = (const float*)d_in[7];
  float* out = (float*)d_out;

  char* ws = (char*)d_ws;
  float* logits = (float*)(ws);
  float* scores = (float*)(ws + 65536);
  int*   sel    = (int*)(ws + 131072);
  int*   rows   = (int*)(ws + 196608);
  float* rwv    = (float*)(ws + 229376);
  unsigned char* W1t = (unsigned char*)(ws + 327680);                     // 4 MB
  unsigned char* W2t = (unsigned char*)(ws + 327680 + 4194304);           // 4 MB
  unsigned char* Xc  = (unsigned char*)(ws + 327680 + 2 * 4194304);       // 8 MB
  unsigned char* H   = (unsigned char*)(ws + 327680 + 2 * 4194304 + 8388608);  // 32 MB

  prep_kernel<<<12288, 256, 0, stream>>>(W1, W1t, W2, W2t, x, Wr, br, logits, scores, out);
  rank_kernel<<<NTOK / 16, 256, 0, stream>>>(scores, sel);
  pack_kernel<<<NB, 1024, 0, stream>>>(scores, sel, rows, rwv);
  gather_kernel<<<MR, 256, 0, stream>>>(x, rows, Xc);
  gemm15<1><<<(MR / 128) * (DFF / 128), 256, 0, stream>>>(
      Xc, W1t, MR, DFF, DIM, b1, H, nullptr, nullptr, nullptr, nullptr);
  gemm15<2><<<(MR / 128) * (DIM / 128), 256, 0, stream>>>(
      H, W2t, MR, DIM, DFF, b2, nullptr, x, rows, rwv, out);
  aux_kernel<<<1, 1024, 0, stream>>>(logits, sel, out, out_size);
}

// Round 18
// 195.561 us; speedup vs baseline: 1.3174x; 1.0265x over previous
//
#include <hip/hip_runtime.h>

#define NB 4
#define SEQ 4096
#define DIM 1024
#define DFF 4096
#define KSEL 2048
#define NTOK (NB * SEQ)   // 16384
#define MR (NB * KSEL)    // 8192

typedef float f32x4_t __attribute__((ext_vector_type(4)));
typedef unsigned long u64_t;
typedef unsigned long u64x2_t __attribute__((ext_vector_type(2)));
typedef int i32x8_t __attribute__((ext_vector_type(8)));

// HW f32->fp8 e4m3 (OCP, RNE, saturating)
__device__ __forceinline__ unsigned char f2fp8(float f) {
  return (unsigned char)(__builtin_amdgcn_cvt_pk_fp8_f32(f, f, 0, false) & 0xff);
}

// fragment-friendly byte permutation within a 128B K-block:
// k = kk*32 + slot*8 + b  ->  pos = slot*32 + kk*8 + b
__device__ __forceinline__ int kperm(int kb) {
  return ((kb >> 3) & 3) * 32 + (kb >> 5) * 8 + (kb & 7);
}

#define GLD16(g, l) __builtin_amdgcn_global_load_lds( \
    (const __attribute__((address_space(1))) void*)(g), \
    (__attribute__((address_space(3))) void*)(l), 16, 0, 0)

// ---- fused prep: W1/W2 transpose+cast (blocks 0..8191) + router GEMV
//      (blocks 8192..12287) ----
__global__ void prep_kernel(const float* __restrict__ W1, unsigned char* __restrict__ W1t,
                            const float* __restrict__ W2, unsigned char* __restrict__ W2t,
                            const float* __restrict__ x, const float* __restrict__ Wr,
                            const float* __restrict__ br,
                            float* __restrict__ logits, float* __restrict__ scores) {
  __shared__ float tl[32][33];
  int bid = blockIdx.x;
  if (bid < 8192) {
    const float* W; unsigned char* Wt; int R, C, bx, by;
    if (bid < 4096) { W = W1; Wt = W1t; R = DIM; C = DFF; bx = bid & 127; by = bid >> 7; }
    else { bid -= 4096; W = W2; Wt = W2t; R = DFF; C = DIM; bx = bid & 31; by = bid >> 5; }
    int c0 = bx * 32;
    int r0 = by * 32;
    int tx = threadIdx.x & 31, ty = threadIdx.x >> 5;
#pragma unroll
    for (int i = 0; i < 4; ++i)
      tl[ty + i * 8][tx] = W[(size_t)(r0 + ty + i * 8) * C + c0 + tx];
    __syncthreads();
    int k = r0 + tx;
    int pos = (k & ~127) + kperm(k & 127);
#pragma unroll
    for (int i = 0; i < 4; ++i)
      Wt[(size_t)(c0 + ty + i * 8) * R + pos] = f2fp8(16.f * tl[tx][ty + i * 8]);
  } else {
    int lane = threadIdx.x & 63;
    int wid  = threadIdx.x >> 6;
    int row  = (bid - 8192) * 4 + wid;        // 0..16383
    const float4* xr = (const float4*)(x + (size_t)row * DIM);
    const float4* w4 = (const float4*)Wr;
    float sum = 0.f;
#pragma unroll
    for (int i = 0; i < 4; ++i) {
      float4 a = xr[lane + i * 64];
      float4 w = w4[lane + i * 64];
      sum += a.x * w.x + a.y * w.y + a.z * w.z + a.w * w.w;
    }
#pragma unroll
    for (int off = 32; off > 0; off >>= 1) sum += __shfl_down(sum, off);
    if (lane == 0) {
      float l = sum + br[0];
      logits[row] = l;
      scores[row] = 1.f / (1.f + expf(-l));
    }
  }
}

// ---- exact top-k via rank counting (matches jax.lax.top_k tie-break) ----
__global__ void rank_kernel(const float* __restrict__ scores, int* __restrict__ sel) {
  __shared__ float s_sc[SEQ];
  int batch = blockIdx.x >> 8;        // 256 blocks per batch
  int chunk = blockIdx.x & 255;
  int t = threadIdx.x;                // 256
  const float4* sb4 = (const float4*)(scores + batch * SEQ);
  float4* ls4 = (float4*)s_sc;
#pragma unroll
  for (int i = 0; i < 4; ++i) ls4[t + i * 256] = sb4[t + i * 256];
  __syncthreads();
  int tok = chunk * 16 + (t >> 4);    // token this thread contributes to
  int sg  = t & 15;                   // score segment 0..15 (256 scores each)
  float s = s_sc[tok];
  const float4* seg = ls4 + sg * 64;
  int jbase = sg * 256;
  int rank = 0;
#pragma unroll 4
  for (int j4 = 0; j4 < 64; ++j4) {
    float4 v = seg[j4];
    int j = jbase + j4 * 4;
    rank += (v.x > s || (v.x == s && j     < tok)) ? 1 : 0;
    rank += (v.y > s || (v.y == s && j + 1 < tok)) ? 1 : 0;
    rank += (v.z > s || (v.z == s && j + 2 < tok)) ? 1 : 0;
    rank += (v.w > s || (v.w == s && j + 3 < tok)) ? 1 : 0;
  }
#pragma unroll
  for (int off = 8; off > 0; off >>= 1) rank += __shfl_down(rank, off, 16);
  if (sg == 0) sel[batch * SEQ + tok] = (rank < KSEL) ? 1 : 0;
}

// ---- per-batch: softmax over selected scores + prefix-sum compaction ----
__global__ void pack_kernel(const float* __restrict__ scores, const int* __restrict__ sel,
                            int* __restrict__ rows, float* __restrict__ rwv,
                            int* __restrict__ slot) {
  __shared__ float red[16];
  __shared__ int scn[1024];
  int batch = blockIdx.x;
  int t = threadIdx.x;
  const float* sb = scores + batch * SEQ;
  const int* fb = sel + batch * SEQ;
  float sc[4]; int fl[4];
#pragma unroll
  for (int i = 0; i < 4; ++i) { sc[i] = sb[t * 4 + i]; fl[i] = fb[t * 4 + i]; }
  float m = fmaxf(fmaxf(sc[0], sc[1]), fmaxf(sc[2], sc[3]));
#pragma unroll
  for (int off = 32; off > 0; off >>= 1) m = fmaxf(m, __shfl_down(m, off));
  if ((t & 63) == 0) red[t >> 6] = m;
  __syncthreads();
  if (t == 0) { float v = red[0]; for (int i = 1; i < 16; ++i) v = fmaxf(v, red[i]); red[0] = v; }
  __syncthreads();
  m = red[0];
  __syncthreads();
  float ex[4]; float esum = 0.f;
#pragma unroll
  for (int i = 0; i < 4; ++i) { ex[i] = expf(sc[i] - m); if (fl[i]) esum += ex[i]; }
#pragma unroll
  for (int off = 32; off > 0; off >>= 1) esum += __shfl_down(esum, off);
  if ((t & 63) == 0) red[t >> 6] = esum;
  __syncthreads();
  if (t == 0) { float v = 0.f; for (int i = 0; i < 16; ++i) v += red[i]; red[0] = v; }
  __syncthreads();
  float total = red[0];
  int cnt = fl[0] + fl[1] + fl[2] + fl[3];
  scn[t] = cnt;
  __syncthreads();
  for (int off = 1; off < 1024; off <<= 1) {
    int a = scn[t];
    int b = (t >= off) ? scn[t - off] : 0;
    __syncthreads();
    scn[t] = a + b;
    __syncthreads();
  }
  int p = scn[t] - cnt;
#pragma unroll
  for (int i = 0; i < 4; ++i) {
    if (fl[i]) {
      rows[batch * KSEL + p] = t * 4 + i;
      rwv[batch * KSEL + p]  = ex[i] / total;
      slot[batch * SEQ + t * 4 + i] = batch * KSEL + p;
      ++p;
    }
  }
}

// ---- fused: selected rows -> fp8 Xc (PANEL-major kperm); unselected -> out ----
// Xc layout: [panel=mrow/128][kt=k/128][slot=pos/32][row=mrow%128][b=pos%32]
__global__ void gather_copy_kernel(const float* __restrict__ x, const int* __restrict__ sel,
                                   const int* __restrict__ slot,
                                   unsigned char* __restrict__ Xc, float* __restrict__ out) {
  int tokg = blockIdx.x;           // 0..16383
  const float4* src = (const float4*)(x + (size_t)tokg * DIM);
  int t = threadIdx.x;             // 256
  float4 v = src[t];
  if (sel[tokg]) {
    unsigned lo = (unsigned)__builtin_amdgcn_cvt_pk_fp8_f32(v.x, v.y, 0, false);
    unsigned both = (unsigned)__builtin_amdgcn_cvt_pk_fp8_f32(v.z, v.w, (int)lo, true);
    int mrow = slot[tokg];
    int panel = mrow >> 7, rowp = mrow & 127;
    int k = t * 4;
    int pos = kperm(k & 127);      // pos % 4 == 0
    size_t addr = (size_t)panel * (128 * DIM) + (size_t)(k >> 7) * 16384
                + (size_t)(pos >> 5) * 4096 + (size_t)rowp * 32 + (pos & 31);
    *(unsigned*)(Xc + addr) = both;
  } else {
    ((float4*)(out + (size_t)tokg * DIM))[t] = v;
  }
}

// ==== MX-FP8 GEMM: panel-major reg-A + dbuf LDS-B, depth-1 counted prefetch ====
// 128x128 tile, BK=128, 256 threads = 4 waves (2M x 2N), wave tile 64x64.
// Per tile: issue A(t+1) [8 dwordx4] + B-stage(t+1) [4 GLD16] = 12 VMEM ops ->
// s_waitcnt vmcnt(12) [exactly tile t's 12 ops complete; t+1 stays in flight]
// -> raw s_barrier -> compute(t) -> s_barrier. Never drains to 0 till the end.
// A panel-major: lanes 0..15 read 512B contiguous (R16-verified).
// B row-major kperm + XOR-swizzle stage (R14-verified, ~2-way conflicts).
// 16 mfma_scale_f32_16x16x128_f8f6f4, scales=1.0 (exact fp8 product).
// W pre-scaled x16 -> epilogue multiplies acc by 1/16.
// EPI=1: H = fp8(gelu(acc/16+b1)) PANEL-major;  EPI=2: out = x + rw*(...)
template <int EPI>
__global__ __launch_bounds__(256)
void gemm16(const unsigned char* __restrict__ A, const unsigned char* __restrict__ Bt,
            int M, int N, int K,
            const float* __restrict__ bias,
            unsigned char* __restrict__ Hout,
            const float* __restrict__ x,
            const int* __restrict__ rows,
            const float* __restrict__ rwv,
            float* __restrict__ out) {
  __shared__ __align__(16) unsigned char Bs[2][128 * 128];   // 32 KB

  const int t = threadIdx.x;
  const int lane = t & 63;
  const int wid = t >> 6;
  const int wm = wid >> 1;                 // 0..1
  const int wn = wid & 1;                  // 0..1

  // XCD-aware bijective swizzle (gridDim.x % 8 == 0 by construction)
  const int nwg = gridDim.x;
  const int qq = nwg >> 3;
  const int nid = (blockIdx.x & 7) * qq + (blockIdx.x >> 3);
  const int gx = N / 128;
  const int by = nid / gx;
  const int bx = nid - by * gx;
  const int bm0 = by * 128;
  const int bn0 = bx * 128;

  const size_t ldb = (size_t)K;            // row BYTES (fp8)
  const char* Bb = (const char*)Bt + (size_t)bn0 * ldb;

  // B staging: thread t covers 16B of each 32-row chunk; row = t>>3 (0..31),
  // dest slot = t&7, source slot = (t&7)^(row&7)
  const int srow = t >> 3;
  const size_t stage_off = (size_t)srow * ldb + (size_t)((((t & 7) ^ (srow & 7)) * 16));

  // B fragment b128 offsets within a 128B kperm row (swizzled 16B units)
  const int cbs0 = ((lane >> 4) * 32     ) ^ ((lane & 7) << 4);
  const int cbs1 = ((lane >> 4) * 32 + 16) ^ ((lane & 7) << 4);

  // A panel-major fragment bases (panel = by)
  const char* Ap = (const char*)A + (size_t)by * 128 * (size_t)K + (size_t)(lane >> 4) * 4096;
  const char* arow[4];
#pragma unroll
  for (int i = 0; i < 4; ++i)
    arow[i] = Ap + (size_t)(wm * 64 + i * 16 + (lane & 15)) * 32;

  f32x4_t acc[4][4];
  f32x4_t zero = {0.f, 0.f, 0.f, 0.f};
#pragma unroll
  for (int i = 0; i < 4; ++i)
#pragma unroll
    for (int j = 0; j < 4; ++j) acc[i][j] = zero;

  const int NT = K / 128;                  // 8 or 32 (even)

  i32x8_t amA[4], amB[4];

  auto loadA = [&](i32x8_t* am, int kt) {
#pragma unroll
    for (int i = 0; i < 4; ++i)
      am[i] = *(const i32x8_t*)(arow[i] + (size_t)kt * 16384);
  };
  auto stageB = [&](int buf, int kt) {
    const size_t kb = (size_t)kt * 128 + stage_off;
    char* dst = (char*)Bs[buf] + t * 16;
#pragma unroll
    for (int c = 0; c < 4; ++c)
      GLD16(Bb + kb + (size_t)(c * 32) * ldb, dst + c * 4096);
  };
  auto compute = [&](const i32x8_t* am, int buf) {
    i32x8_t bq[4];
#pragma unroll
    for (int j = 0; j < 4; ++j) {
      const char* bp = (const char*)Bs[buf] + (wn * 64 + j * 16 + (lane & 15)) * 128;
      union { u64x2_t q[2]; i32x8_t v; } u;
      u.q[0] = *(const u64x2_t*)(bp + cbs0);
      u.q[1] = *(const u64x2_t*)(bp + cbs1);
      bq[j] = u.v;
    }
    __builtin_amdgcn_s_setprio(1);
#pragma unroll
    for (int i = 0; i < 4; ++i)
#pragma unroll
      for (int j = 0; j < 4; ++j)
        acc[i][j] = __builtin_amdgcn_mfma_scale_f32_16x16x128_f8f6f4(
            am[i], bq[j], acc[i][j], 0, 0,
            0, 0x7f7f7f7f, 0, 0x7f7f7f7f);   // E8M0 0x7f = 1.0 scales
    __builtin_amdgcn_s_setprio(0);
  };

  // prologue: tile 0 in flight
  loadA(amA, 0);
  stageB(0, 0);

  for (int kt = 0; kt < NT; kt += 2) {
    // ---- phase 1: compute kt (amA, buf0), prefetch kt+1 ----
    loadA(amB, kt + 1);                    // NT even => kt+1 < NT always
    stageB(1, kt + 1);
    asm volatile("s_waitcnt vmcnt(12)" ::: "memory");
    __builtin_amdgcn_s_barrier();
    __builtin_amdgcn_sched_barrier(0);
    compute(amA, 0);
    __builtin_amdgcn_s_barrier();
    // ---- phase 2: compute kt+1 (amB, buf1), prefetch kt+2 ----
    if (kt + 2 < NT) {
      loadA(amA, kt + 2);
      stageB(0, kt + 2);
      asm volatile("s_waitcnt vmcnt(12)" ::: "memory");
    } else {
      asm volatile("s_waitcnt vmcnt(0)" ::: "memory");
    }
    __builtin_amdgcn_s_barrier();
    __builtin_amdgcn_sched_barrier(0);
    compute(amB, 1);
    __builtin_amdgcn_s_barrier();
  }

  // epilogue  (C/D: row = (lane>>4)*4 + qi (M), col = lane&15 (N))
  const int rb = (lane >> 4) * 4;
  const int cc = lane & 15;
#pragma unroll
  for (int i = 0; i < 4; ++i) {
#pragma unroll
    for (int qi = 0; qi < 4; ++qi) {
      int grow = bm0 + wm * 64 + i * 16 + rb + qi;
      if (EPI == 1) {
        int panel = grow >> 7, rowp = grow & 127;
#pragma unroll
        for (int j = 0; j < 4; ++j) {
          int gcol = bn0 + wn * 64 + j * 16 + cc;
          float v = acc[i][j][qi] * 0.0625f + bias[gcol];
          float cp = 0.7978845608028654f * (v + 0.044715f * v * v * v);
          float g = v / (1.f + __expf(-2.f * cp));   // tanh-approx gelu
          int pos = kperm(gcol & 127);
          size_t addr = (size_t)panel * (128 * DFF) + (size_t)(gcol >> 7) * 16384
                      + (size_t)(pos >> 5) * 4096 + (size_t)rowp * 32 + (pos & 31);
          Hout[addr] = f2fp8(g);
        }
      } else {
        int batch = grow >> 11;
        int tok = rows[grow];
        float rw = rwv[grow];
        size_t obase = ((size_t)(batch * SEQ + tok)) * DIM;
#pragma unroll
        for (int j = 0; j < 4; ++j) {
          int gcol = bn0 + wn * 64 + j * 16 + cc;
          float v = acc[i][j][qi] * 0.0625f + bias[gcol];
          out[obase + gcol] = x[obase + gcol] + rw * v;
        }
      }
    }
  }
}

// ---- aux BCE loss reduction ----
__global__ void aux_kernel(const float* __restrict__ logits, const int* __restrict__ sel,
                           float* __restrict__ out, int out_size) {
  __shared__ float red[16];
  int t = threadIdx.x;
  float sum = 0.f;
  for (int i = t; i < NTOK; i += 1024) {
    float l = logits[i];
    float tgt = sel[i] ? 1.f : 0.f;
    sum += fmaxf(l, 0.f) - l * tgt + log1pf(expf(-fabsf(l)));
  }
#pragma unroll
  for (int off = 32; off > 0; off >>= 1) sum += __shfl_down(sum, off);
  if ((t & 63) == 0) red[t >> 6] = sum;
  __syncthreads();
  if (t == 0) {
    float v = 0.f;
    for (int i = 0; i < 16; ++i) v += red[i];
    out[out_size - 1] = v / (float)NTOK;
  }
}

extern "C" void kernel_launch(void* const* d_in, const int* in_sizes, int n_in,
                              void* d_out, int out_size, void* d_ws, size_t ws_size,
                              hipStream_t stream) {
  const float* x  = (const float*)d_in[0];
  // d_in[1] = attention_mask (unused by reference)
  const float* Wr = (const float*)d_in[2];
  const float* br = (const float*)d_in[3];
  const float* W1 = (const float*)d_in[4];
  const float* b1 = (const float*)d_in[5];
  const float* W2 = (const float*)d_in[6];
  const float* b2 = (const float*)d_in[7];
  float* out = (float*)d_out;

  char* ws = (char*)d_ws;
  float* logits = (float*)(ws);
  float* scores = (float*)(ws + 65536);
  int*   sel    = (int*)(ws + 131072);
  int*   rows   = (int*)(ws + 196608);
  float* rwv    = (float*)(ws + 229376);
  int*   slot   = (int*)(ws + 262144);
  unsigned char* W1t = (unsigned char*)(ws + 327680);                     // 4 MB
  unsigned char* W2t = (unsigned char*)(ws + 327680 + 4194304);           // 4 MB
  unsigned char* Xc  = (unsigned char*)(ws + 327680 + 2 * 4194304);       // 8 MB
  unsigned char* H   = (unsigned char*)(ws + 327680 + 2 * 4194304 + 8388608);  // 32 MB

  prep_kernel<<<12288, 256, 0, stream>>>(W1, W1t, W2, W2t, x, Wr, br, logits, scores);
  rank_kernel<<<NTOK / 16, 256, 0, stream>>>(scores, sel);
  pack_kernel<<<NB, 1024, 0, stream>>>(scores, sel, rows, rwv, slot);
  gather_copy_kernel<<<NTOK, 256, 0, stream>>>(x, sel, slot, Xc, out);
  gemm16<1><<<(MR / 128) * (DFF / 128), 256, 0, stream>>>(
      Xc, W1t, MR, DFF, DIM, b1, H, nullptr, nullptr, nullptr, nullptr);
  gemm16<2><<<(MR / 128) * (DIM / 128), 256, 0, stream>>>(
      H, W2t, MR, DIM, DFF, b2, nullptr, x, rows, rwv, out);
  aux_kernel<<<1, 1024, 0, stream>>>(logits, sel, out, out_size);
}

// Round 19
// 193.617 us; speedup vs baseline: 1.3307x; 1.0100x over previous
//
#include <hip/hip_runtime.h>

#define NB 4
#define SEQ 4096
#define DIM 1024
#define DFF 4096
#define KSEL 2048
#define NTOK (NB * SEQ)   // 16384
#define MR (NB * KSEL)    // 8192

typedef float f32x4_t __attribute__((ext_vector_type(4)));
typedef unsigned long u64_t;
typedef unsigned long u64x2_t __attribute__((ext_vector_type(2)));
typedef int i32x8_t __attribute__((ext_vector_type(8)));

// HW f32->fp8 e4m3 (OCP, RNE, saturating)
__device__ __forceinline__ unsigned char f2fp8(float f) {
  return (unsigned char)(__builtin_amdgcn_cvt_pk_fp8_f32(f, f, 0, false) & 0xff);
}

// fragment-friendly byte permutation within a 128B K-block:
// k = kk*32 + slot*8 + b  ->  pos = slot*32 + kk*8 + b
__device__ __forceinline__ int kperm(int kb) {
  return ((kb >> 3) & 3) * 32 + (kb >> 5) * 8 + (kb & 7);
}

#define GLD16(g, l) __builtin_amdgcn_global_load_lds( \
    (const __attribute__((address_space(1))) void*)(g), \
    (__attribute__((address_space(3))) void*)(l), 16, 0, 0)

// ---- fused prep: W1/W2 transpose+cast (blocks 0..8191) + router GEMV
//      (blocks 8192..12287) ----
__global__ void prep_kernel(const float* __restrict__ W1, unsigned char* __restrict__ W1t,
                            const float* __restrict__ W2, unsigned char* __restrict__ W2t,
                            const float* __restrict__ x, const float* __restrict__ Wr,
                            const float* __restrict__ br,
                            float* __restrict__ logits, float* __restrict__ scores) {
  __shared__ float tl[32][33];
  int bid = blockIdx.x;
  if (bid < 8192) {
    const float* W; unsigned char* Wt; int R, C, bx, by;
    if (bid < 4096) { W = W1; Wt = W1t; R = DIM; C = DFF; bx = bid & 127; by = bid >> 7; }
    else { bid -= 4096; W = W2; Wt = W2t; R = DFF; C = DIM; bx = bid & 31; by = bid >> 5; }
    int c0 = bx * 32;
    int r0 = by * 32;
    int tx = threadIdx.x & 31, ty = threadIdx.x >> 5;
#pragma unroll
    for (int i = 0; i < 4; ++i)
      tl[ty + i * 8][tx] = W[(size_t)(r0 + ty + i * 8) * C + c0 + tx];
    __syncthreads();
    int k = r0 + tx;
    int pos = (k & ~127) + kperm(k & 127);
#pragma unroll
    for (int i = 0; i < 4; ++i)
      Wt[(size_t)(c0 + ty + i * 8) * R + pos] = f2fp8(16.f * tl[tx][ty + i * 8]);
  } else {
    int lane = threadIdx.x & 63;
    int wid  = threadIdx.x >> 6;
    int row  = (bid - 8192) * 4 + wid;        // 0..16383
    const float4* xr = (const float4*)(x + (size_t)row * DIM);
    const float4* w4 = (const float4*)Wr;
    float sum = 0.f;
#pragma unroll
    for (int i = 0; i < 4; ++i) {
      float4 a = xr[lane + i * 64];
      float4 w = w4[lane + i * 64];
      sum += a.x * w.x + a.y * w.y + a.z * w.z + a.w * w.w;
    }
#pragma unroll
    for (int off = 32; off > 0; off >>= 1) sum += __shfl_down(sum, off);
    if (lane == 0) {
      float l = sum + br[0];
      logits[row] = l;
      scores[row] = 1.f / (1.f + expf(-l));
    }
  }
}

// ---- exact top-k via rank counting (matches jax.lax.top_k tie-break) ----
__global__ void rank_kernel(const float* __restrict__ scores, int* __restrict__ sel) {
  __shared__ float s_sc[SEQ];
  int batch = blockIdx.x >> 8;        // 256 blocks per batch
  int chunk = blockIdx.x & 255;
  int t = threadIdx.x;                // 256
  const float4* sb4 = (const float4*)(scores + batch * SEQ);
  float4* ls4 = (float4*)s_sc;
#pragma unroll
  for (int i = 0; i < 4; ++i) ls4[t + i * 256] = sb4[t + i * 256];
  __syncthreads();
  int tok = chunk * 16 + (t >> 4);    // token this thread contributes to
  int sg  = t & 15;                   // score segment 0..15 (256 scores each)
  float s = s_sc[tok];
  const float4* seg = ls4 + sg * 64;
  int jbase = sg * 256;
  int rank = 0;
#pragma unroll 4
  for (int j4 = 0; j4 < 64; ++j4) {
    float4 v = seg[j4];
    int j = jbase + j4 * 4;
    rank += (v.x > s || (v.x == s && j     < tok)) ? 1 : 0;
    rank += (v.y > s || (v.y == s && j + 1 < tok)) ? 1 : 0;
    rank += (v.z > s || (v.z == s && j + 2 < tok)) ? 1 : 0;
    rank += (v.w > s || (v.w == s && j + 3 < tok)) ? 1 : 0;
  }
#pragma unroll
  for (int off = 8; off > 0; off >>= 1) rank += __shfl_down(rank, off, 16);
  if (sg == 0) sel[batch * SEQ + tok] = (rank < KSEL) ? 1 : 0;
}

// ---- per-batch: softmax over selected scores + prefix-sum compaction ----
__global__ void pack_kernel(const float* __restrict__ scores, const int* __restrict__ sel,
                            int* __restrict__ rows, float* __restrict__ rwv,
                            int* __restrict__ slot) {
  __shared__ float red[16];
  __shared__ int scn[1024];
  int batch = blockIdx.x;
  int t = threadIdx.x;
  const float* sb = scores + batch * SEQ;
  const int* fb = sel + batch * SEQ;
  float sc[4]; int fl[4];
#pragma unroll
  for (int i = 0; i < 4; ++i) { sc[i] = sb[t * 4 + i]; fl[i] = fb[t * 4 + i]; }
  float m = fmaxf(fmaxf(sc[0], sc[1]), fmaxf(sc[2], sc[3]));
#pragma unroll
  for (int off = 32; off > 0; off >>= 1) m = fmaxf(m, __shfl_down(m, off));
  if ((t & 63) == 0) red[t >> 6] = m;
  __syncthreads();
  if (t == 0) { float v = red[0]; for (int i = 1; i < 16; ++i) v = fmaxf(v, red[i]); red[0] = v; }
  __syncthreads();
  m = red[0];
  __syncthreads();
  float ex[4]; float esum = 0.f;
#pragma unroll
  for (int i = 0; i < 4; ++i) { ex[i] = expf(sc[i] - m); if (fl[i]) esum += ex[i]; }
#pragma unroll
  for (int off = 32; off > 0; off >>= 1) esum += __shfl_down(esum, off);
  if ((t & 63) == 0) red[t >> 6] = esum;
  __syncthreads();
  if (t == 0) { float v = 0.f; for (int i = 0; i < 16; ++i) v += red[i]; red[0] = v; }
  __syncthreads();
  float total = red[0];
  int cnt = fl[0] + fl[1] + fl[2] + fl[3];
  scn[t] = cnt;
  __syncthreads();
  for (int off = 1; off < 1024; off <<= 1) {
    int a = scn[t];
    int b = (t >= off) ? scn[t - off] : 0;
    __syncthreads();
    scn[t] = a + b;
    __syncthreads();
  }
  int p = scn[t] - cnt;
#pragma unroll
  for (int i = 0; i < 4; ++i) {
    if (fl[i]) {
      rows[batch * KSEL + p] = t * 4 + i;
      rwv[batch * KSEL + p]  = ex[i] / total;
      slot[batch * SEQ + t * 4 + i] = batch * KSEL + p;
      ++p;
    }
  }
}

// ---- fused: selected rows -> fp8 Xc (PANEL-major kperm); unselected -> out ----
// Xc layout: [panel=mrow/128][kt=k/128][slot=pos/32][row=mrow%128][b=pos%32]
__global__ void gather_copy_kernel(const float* __restrict__ x, const int* __restrict__ sel,
                                   const int* __restrict__ slot,
                                   unsigned char* __restrict__ Xc, float* __restrict__ out) {
  int tokg = blockIdx.x;           // 0..16383
  const float4* src = (const float4*)(x + (size_t)tokg * DIM);
  int t = threadIdx.x;             // 256
  float4 v = src[t];
  if (sel[tokg]) {
    unsigned lo = (unsigned)__builtin_amdgcn_cvt_pk_fp8_f32(v.x, v.y, 0, false);
    unsigned both = (unsigned)__builtin_amdgcn_cvt_pk_fp8_f32(v.z, v.w, (int)lo, true);
    int mrow = slot[tokg];
    int panel = mrow >> 7, rowp = mrow & 127;
    int k = t * 4;
    int pos = kperm(k & 127);      // pos % 4 == 0
    size_t addr = (size_t)panel * (128 * DIM) + (size_t)(k >> 7) * 16384
                + (size_t)(pos >> 5) * 4096 + (size_t)rowp * 32 + (pos & 31);
    *(unsigned*)(Xc + addr) = both;
  } else {
    ((float4*)(out + (size_t)tokg * DIM))[t] = v;
  }
}

// ==== MX-FP8 GEMM: panel-major reg-A + LDS-B, DEPTH-2 counted prefetch ====
// 128x128 tile, BK=128, 256 threads = 4 waves (2M x 2N), wave tile 64x64.
// Triple-buffered B (3x16KB LDS) + triple A-register sets (unroll-by-3 makes
// all indices compile-time). Per tile T: issue tile T+2's group [8 dwordx4 A
// + 4 GLD16 B = 12 VMEM ops] -> s_waitcnt vmcnt(24) [groups T+1,T+2 in
// flight; T complete -- 2 tiles (~2600cyc) of latency cover] -> raw s_barrier
// -> compute(T) -> s_barrier. Tail: vmcnt(12)/vmcnt(0).
// A panel-major: lanes 0..15 read 512B contiguous (R16-verified).
// B row-major kperm + XOR-swizzle stage (R14-verified, ~2-way conflicts).
// 16 mfma_scale_f32_16x16x128_f8f6f4, scales=1.0 (exact fp8 product).
// W pre-scaled x16 -> epilogue multiplies acc by 1/16.
// EPI=1: H = fp8(gelu(acc/16+b1)) PANEL-major;  EPI=2: out = x + rw*(...)
template <int EPI>
__global__ __launch_bounds__(256)
void gemm17(const unsigned char* __restrict__ A, const unsigned char* __restrict__ Bt,
            int M, int N, int K,
            const float* __restrict__ bias,
            unsigned char* __restrict__ Hout,
            const float* __restrict__ x,
            const int* __restrict__ rows,
            const float* __restrict__ rwv,
            float* __restrict__ out) {
  __shared__ __align__(16) unsigned char Bs[3][128 * 128];   // 48 KB

  const int t = threadIdx.x;
  const int lane = t & 63;
  const int wid = t >> 6;
  const int wm = wid >> 1;                 // 0..1
  const int wn = wid & 1;                  // 0..1

  // XCD-aware bijective swizzle (gridDim.x % 8 == 0 by construction)
  const int nwg = gridDim.x;
  const int qq = nwg >> 3;
  const int nid = (blockIdx.x & 7) * qq + (blockIdx.x >> 3);
  const int gx = N / 128;
  const int by = nid / gx;
  const int bx = nid - by * gx;
  const int bm0 = by * 128;
  const int bn0 = bx * 128;

  const size_t ldb = (size_t)K;            // row BYTES (fp8)
  const char* Bb = (const char*)Bt + (size_t)bn0 * ldb;

  // B staging: thread t covers 16B of each 32-row chunk; row = t>>3 (0..31),
  // dest slot = t&7, source slot = (t&7)^(row&7)
  const int srow = t >> 3;
  const size_t stage_off = (size_t)srow * ldb + (size_t)((((t & 7) ^ (srow & 7)) * 16));

  // B fragment b128 offsets within a 128B kperm row (swizzled 16B units)
  const int cbs0 = ((lane >> 4) * 32     ) ^ ((lane & 7) << 4);
  const int cbs1 = ((lane >> 4) * 32 + 16) ^ ((lane & 7) << 4);

  // A panel-major fragment bases (panel = by)
  const char* Ap = (const char*)A + (size_t)by * 128 * (size_t)K + (size_t)(lane >> 4) * 4096;
  const char* arow[4];
#pragma unroll
  for (int i = 0; i < 4; ++i)
    arow[i] = Ap + (size_t)(wm * 64 + i * 16 + (lane & 15)) * 32;

  f32x4_t acc[4][4];
  f32x4_t zero = {0.f, 0.f, 0.f, 0.f};
#pragma unroll
  for (int i = 0; i < 4; ++i)
#pragma unroll
    for (int j = 0; j < 4; ++j) acc[i][j] = zero;

  const int NT = K / 128;                  // 8 or 32

  i32x8_t am[3][4];                        // 3 A-register sets (rotated, static idx)

  auto loadA = [&](i32x8_t* dst, int kt) {
#pragma unroll
    for (int i = 0; i < 4; ++i)
      dst[i] = *(const i32x8_t*)(arow[i] + (size_t)kt * 16384);
  };
  auto stageB = [&](int buf, int kt) {
    const size_t kb = (size_t)kt * 128 + stage_off;
    char* dst = (char*)Bs[buf] + t * 16;
#pragma unroll
    for (int c = 0; c < 4; ++c)
      GLD16(Bb + kb + (size_t)(c * 32) * ldb, dst + c * 4096);
  };
  auto compute = [&](const i32x8_t* a, int buf) {
    i32x8_t bq[4];
#pragma unroll
    for (int j = 0; j < 4; ++j) {
      const char* bp = (const char*)Bs[buf] + (wn * 64 + j * 16 + (lane & 15)) * 128;
      union { u64x2_t q[2]; i32x8_t v; } u;
      u.q[0] = *(const u64x2_t*)(bp + cbs0);
      u.q[1] = *(const u64x2_t*)(bp + cbs1);
      bq[j] = u.v;
    }
    __builtin_amdgcn_s_setprio(1);
#pragma unroll
    for (int i = 0; i < 4; ++i)
#pragma unroll
      for (int j = 0; j < 4; ++j)
        acc[i][j] = __builtin_amdgcn_mfma_scale_f32_16x16x128_f8f6f4(
            a[i], bq[j], acc[i][j], 0, 0,
            0, 0x7f7f7f7f, 0, 0x7f7f7f7f);   // E8M0 0x7f = 1.0 scales
    __builtin_amdgcn_s_setprio(0);
  };

  // prologue: tiles 0 and 1 in flight (24 VMEM ops)
  loadA(am[0], 0); stageB(0, 0);
  loadA(am[1], 1); stageB(1, 1);

  for (int kt = 0; kt < NT; kt += 3) {
#pragma unroll
    for (int b = 0; b < 3; ++b) {
      const int T = kt + b;
      if (T < NT) {
        const int nb = (b + 2) % 3;          // compile-time after unroll
        if (T + 2 < NT) {
          loadA(am[nb], T + 2);
          stageB(nb, T + 2);
          asm volatile("s_waitcnt vmcnt(24)" ::: "memory");   // T done; T+1,T+2 in flight
        } else if (T + 1 < NT) {
          asm volatile("s_waitcnt vmcnt(12)" ::: "memory");   // T done; T+1 in flight
        } else {
          asm volatile("s_waitcnt vmcnt(0)" ::: "memory");    // last tile
        }
        __builtin_amdgcn_s_barrier();
        __builtin_amdgcn_sched_barrier(0);
        compute(am[b], b);
        __builtin_amdgcn_s_barrier();
      }
    }
  }

  // epilogue  (C/D: row = (lane>>4)*4 + qi (M), col = lane&15 (N))
  const int rb = (lane >> 4) * 4;
  const int cc = lane & 15;
#pragma unroll
  for (int i = 0; i < 4; ++i) {
#pragma unroll
    for (int qi = 0; qi < 4; ++qi) {
      int grow = bm0 + wm * 64 + i * 16 + rb + qi;
      if (EPI == 1) {
        int panel = grow >> 7, rowp = grow & 127;
#pragma unroll
        for (int j = 0; j < 4; ++j) {
          int gcol = bn0 + wn * 64 + j * 16 + cc;
          float v = acc[i][j][qi] * 0.0625f + bias[gcol];
          float cp = 0.7978845608028654f * (v + 0.044715f * v * v * v);
          float g = v / (1.f + __expf(-2.f * cp));   // tanh-approx gelu
          int pos = kperm(gcol & 127);
          size_t addr = (size_t)panel * (128 * DFF) + (size_t)(gcol >> 7) * 16384
                      + (size_t)(pos >> 5) * 4096 + (size_t)rowp * 32 + (pos & 31);
          Hout[addr] = f2fp8(g);
        }
      } else {
        int batch = grow >> 11;
        int tok = rows[grow];
        float rw = rwv[grow];
        size_t obase = ((size_t)(batch * SEQ + tok)) * DIM;
#pragma unroll
        for (int j = 0; j < 4; ++j) {
          int gcol = bn0 + wn * 64 + j * 16 + cc;
          float v = acc[i][j][qi] * 0.0625f + bias[gcol];
          out[obase + gcol] = x[obase + gcol] + rw * v;
        }
      }
    }
  }
}

// ---- aux BCE loss reduction ----
__global__ void aux_kernel(const float* __restrict__ logits, const int* __restrict__ sel,
                           float* __restrict__ out, int out_size) {
  __shared__ float red[16];
  int t = threadIdx.x;
  float sum = 0.f;
  for (int i = t; i < NTOK; i += 1024) {
    float l = logits[i];
    float tgt = sel[i] ? 1.f : 0.f;
    sum += fmaxf(l, 0.f) - l * tgt + log1pf(expf(-fabsf(l)));
  }
#pragma unroll
  for (int off = 32; off > 0; off >>= 1) sum += __shfl_down(sum, off);
  if ((t & 63) == 0) red[t >> 6] = sum;
  __syncthreads();
  if (t == 0) {
    float v = 0.f;
    for (int i = 0; i < 16; ++i) v += red[i];
    out[out_size - 1] = v / (float)NTOK;
  }
}

extern "C" void kernel_launch(void* const* d_in, const int* in_sizes, int n_in,
                              void* d_out, int out_size, void* d_ws, size_t ws_size,
                              hipStream_t stream) {
  const float* x  = (const float*)d_in[0];
  // d_in[1] = attention_mask (unused by reference)
  const float* Wr = (const float*)d_in[2];
  const float* br = (const float*)d_in[3];
  const float* W1 = (const float*)d_in[4];
  const float* b1 = (const float*)d_in[5];
  const float* W2 = (const float*)d_in[6];
  const float* b2 = (const float*)d_in[7];
  float* out = (float*)d_out;

  char* ws = (char*)d_ws;
  float* logits = (float*)(ws);
  float* scores = (float*)(ws + 65536);
  int*   sel    = (int*)(ws + 131072);
  int*   rows   = (int*)(ws + 196608);
  float* rwv    = (float*)(ws + 229376);
  int*   slot   = (int*)(ws + 262144);
  unsigned char* W1t = (unsigned char*)(ws + 327680);                     // 4 MB
  unsigned char* W2t = (unsigned char*)(ws + 327680 + 4194304);           // 4 MB
  unsigned char* Xc  = (unsigned char*)(ws + 327680 + 2 * 4194304);       // 8 MB
  unsigned char* H   = (unsigned char*)(ws + 327680 + 2 * 4194304 + 8388608);  // 32 MB

  prep_kernel<<<12288, 256, 0, stream>>>(W1, W1t, W2, W2t, x, Wr, br, logits, scores);
  rank_kernel<<<NTOK / 16, 256, 0, stream>>>(scores, sel);
  pack_kernel<<<NB, 1024, 0, stream>>>(scores, sel, rows, rwv, slot);
  gather_copy_kernel<<<NTOK, 256, 0, stream>>>(x, sel, slot, Xc, out);
  gemm17<1><<<(MR / 128) * (DFF / 128), 256, 0, stream>>>(
      Xc, W1t, MR, DFF, DIM, b1, H, nullptr, nullptr, nullptr, nullptr);
  gemm17<2><<<(MR / 128) * (DIM / 128), 256, 0, stream>>>(
      H, W2t, MR, DIM, DFF, b2, nullptr, x, rows, rwv, out);
  aux_kernel<<<1, 1024, 0, stream>>>(logits, sel, out, out_size);
}

// Round 20
// 181.468 us; speedup vs baseline: 1.4198x; 1.0670x over previous
//
#include <hip/hip_runtime.h>

#define NB 4
#define SEQ 4096
#define DIM 1024
#define DFF 4096
#define KSEL 2048
#define NTOK (NB * SEQ)   // 16384
#define MR (NB * KSEL)    // 8192

typedef float f32x4_t __attribute__((ext_vector_type(4)));
typedef unsigned long u64_t;
typedef unsigned long u64x2_t __attribute__((ext_vector_type(2)));
typedef int i32x8_t __attribute__((ext_vector_type(8)));

// HW f32->fp8 e4m3 (OCP, RNE, saturating)
__device__ __forceinline__ unsigned char f2fp8(float f) {
  return (unsigned char)(__builtin_amdgcn_cvt_pk_fp8_f32(f, f, 0, false) & 0xff);
}

// fragment-friendly byte permutation within a 128B K-block:
// k = kk*32 + slot*8 + b  ->  pos = slot*32 + kk*8 + b
__device__ __forceinline__ int kperm(int kb) {
  return ((kb >> 3) & 3) * 32 + (kb >> 5) * 8 + (kb & 7);
}

#define GLD16(g, l) __builtin_amdgcn_global_load_lds( \
    (const __attribute__((address_space(1))) void*)(g), \
    (__attribute__((address_space(3))) void*)(l), 16, 0, 0)

// ---- fused prep: W1/W2 transpose+cast (blocks 0..8191) + router GEMV
//      (blocks 8192..12287) ----
__global__ void prep_kernel(const float* __restrict__ W1, unsigned char* __restrict__ W1t,
                            const float* __restrict__ W2, unsigned char* __restrict__ W2t,
                            const float* __restrict__ x, const float* __restrict__ Wr,
                            const float* __restrict__ br,
                            float* __restrict__ logits, float* __restrict__ scores) {
  __shared__ float tl[32][33];
  int bid = blockIdx.x;
  if (bid < 8192) {
    const float* W; unsigned char* Wt; int R, C, bx, by;
    if (bid < 4096) { W = W1; Wt = W1t; R = DIM; C = DFF; bx = bid & 127; by = bid >> 7; }
    else { bid -= 4096; W = W2; Wt = W2t; R = DFF; C = DIM; bx = bid & 31; by = bid >> 5; }
    int c0 = bx * 32;
    int r0 = by * 32;
    int tx = threadIdx.x & 31, ty = threadIdx.x >> 5;
#pragma unroll
    for (int i = 0; i < 4; ++i)
      tl[ty + i * 8][tx] = W[(size_t)(r0 + ty + i * 8) * C + c0 + tx];
    __syncthreads();
    int k = r0 + tx;
    int pos = (k & ~127) + kperm(k & 127);
#pragma unroll
    for (int i = 0; i < 4; ++i)
      Wt[(size_t)(c0 + ty + i * 8) * R + pos] = f2fp8(16.f * tl[tx][ty + i * 8]);
  } else {
    int lane = threadIdx.x & 63;
    int wid  = threadIdx.x >> 6;
    int row  = (bid - 8192) * 4 + wid;        // 0..16383
    const float4* xr = (const float4*)(x + (size_t)row * DIM);
    const float4* w4 = (const float4*)Wr;
    float sum = 0.f;
#pragma unroll
    for (int i = 0; i < 4; ++i) {
      float4 a = xr[lane + i * 64];
      float4 w = w4[lane + i * 64];
      sum += a.x * w.x + a.y * w.y + a.z * w.z + a.w * w.w;
    }
#pragma unroll
    for (int off = 32; off > 0; off >>= 1) sum += __shfl_down(sum, off);
    if (lane == 0) {
      float l = sum + br[0];
      logits[row] = l;
      scores[row] = 1.f / (1.f + expf(-l));
    }
  }
}

// ---- exact top-k via rank counting (matches jax.lax.top_k tie-break) ----
__global__ void rank_kernel(const float* __restrict__ scores, int* __restrict__ sel) {
  __shared__ float s_sc[SEQ];
  int batch = blockIdx.x >> 8;        // 256 blocks per batch
  int chunk = blockIdx.x & 255;
  int t = threadIdx.x;                // 256
  const float4* sb4 = (const float4*)(scores + batch * SEQ);
  float4* ls4 = (float4*)s_sc;
#pragma unroll
  for (int i = 0; i < 4; ++i) ls4[t + i * 256] = sb4[t + i * 256];
  __syncthreads();
  int tok = chunk * 16 + (t >> 4);    // token this thread contributes to
  int sg  = t & 15;                   // score segment 0..15 (256 scores each)
  float s = s_sc[tok];
  const float4* seg = ls4 + sg * 64;
  int jbase = sg * 256;
  int rank = 0;
#pragma unroll 4
  for (int j4 = 0; j4 < 64; ++j4) {
    float4 v = seg[j4];
    int j = jbase + j4 * 4;
    rank += (v.x > s || (v.x == s && j     < tok)) ? 1 : 0;
    rank += (v.y > s || (v.y == s && j + 1 < tok)) ? 1 : 0;
    rank += (v.z > s || (v.z == s && j + 2 < tok)) ? 1 : 0;
    rank += (v.w > s || (v.w == s && j + 3 < tok)) ? 1 : 0;
  }
#pragma unroll
  for (int off = 8; off > 0; off >>= 1) rank += __shfl_down(rank, off, 16);
  if (sg == 0) sel[batch * SEQ + tok] = (rank < KSEL) ? 1 : 0;
}

// ---- per-batch: softmax over selected + compaction + BCE partial ----
// Scan: wave-level __shfl_up inclusive scan (no barriers) + 16-entry
// cross-wave exclusive scan. Replaces the 20-barrier O(n log n) scan.
__global__ void pack_kernel(const float* __restrict__ scores, const int* __restrict__ sel,
                            const float* __restrict__ logits,
                            int* __restrict__ rows, float* __restrict__ rwv,
                            int* __restrict__ slot, float* __restrict__ aux_part) {
  __shared__ float red[16];
  __shared__ int wsum[16];
  int batch = blockIdx.x;
  int t = threadIdx.x;
  int lane = t & 63, wid = t >> 6;
  const float* sb = scores + batch * SEQ;
  const int* fb = sel + batch * SEQ;
  float sc[4]; int fl[4];
#pragma unroll
  for (int i = 0; i < 4; ++i) { sc[i] = sb[t * 4 + i]; fl[i] = fb[t * 4 + i]; }
  // ---- block max ----
  float m = fmaxf(fmaxf(sc[0], sc[1]), fmaxf(sc[2], sc[3]));
#pragma unroll
  for (int off = 32; off > 0; off >>= 1) m = fmaxf(m, __shfl_down(m, off));
  if (lane == 0) red[wid] = m;
  __syncthreads();
  if (t == 0) { float v = red[0]; for (int i = 1; i < 16; ++i) v = fmaxf(v, red[i]); red[0] = v; }
  __syncthreads();
  m = red[0];
  __syncthreads();
  // ---- selected-exp sum ----
  float ex[4]; float esum = 0.f;
#pragma unroll
  for (int i = 0; i < 4; ++i) { ex[i] = expf(sc[i] - m); if (fl[i]) esum += ex[i]; }
#pragma unroll
  for (int off = 32; off > 0; off >>= 1) esum += __shfl_down(esum, off);
  if (lane == 0) red[wid] = esum;
  __syncthreads();
  if (t == 0) { float v = 0.f; for (int i = 0; i < 16; ++i) v += red[i]; red[0] = v; }
  __syncthreads();
  float total = red[0];
  __syncthreads();
  // ---- BCE partial for this batch ----
  const float* lb = logits + batch * SEQ;
  float bce = 0.f;
#pragma unroll
  for (int i = 0; i < 4; ++i) {
    float l = lb[t * 4 + i];
    float tgt = fl[i] ? 1.f : 0.f;
    bce += fmaxf(l, 0.f) - l * tgt + log1pf(expf(-fabsf(l)));
  }
#pragma unroll
  for (int off = 32; off > 0; off >>= 1) bce += __shfl_down(bce, off);
  if (lane == 0) red[wid] = bce;
  // ---- wave-level scan of counts (no barrier needed yet) ----
  int cnt = fl[0] + fl[1] + fl[2] + fl[3];
  int inc = cnt;
#pragma unroll
  for (int off = 1; off < 64; off <<= 1) {
    int n = __shfl_up(inc, off);
    if (lane >= off) inc += n;
  }
  if (lane == 63) wsum[wid] = inc;
  __syncthreads();
  if (t == 0) {
    float v = 0.f;
    for (int i = 0; i < 16; ++i) v += red[i];
    aux_part[batch] = v;
    int a = 0;
    for (int i = 0; i < 16; ++i) { int w = wsum[i]; wsum[i] = a; a += w; }
  }
  __syncthreads();
  int p = wsum[wid] + inc - cnt;       // exclusive prefix in token order
#pragma unroll
  for (int i = 0; i < 4; ++i) {
    if (fl[i]) {
      rows[batch * KSEL + p] = t * 4 + i;
      rwv[batch * KSEL + p]  = ex[i] / total;
      slot[batch * SEQ + t * 4 + i] = batch * KSEL + p;
      ++p;
    }
  }
}

// ---- tiny final: aux loss = mean of 4 batch partials ----
__global__ void aux_final(const float* __restrict__ aux_part, float* __restrict__ out,
                          int out_size) {
  if (threadIdx.x == 0)
    out[out_size - 1] = (aux_part[0] + aux_part[1] + aux_part[2] + aux_part[3]) / (float)NTOK;
}

// ---- fused: selected rows -> fp8 Xc (PANEL-major kperm); unselected -> out ----
// Xc layout: [panel=mrow/128][kt=k/128][slot=pos/32][row=mrow%128][b=pos%32]
__global__ void gather_copy_kernel(const float* __restrict__ x, const int* __restrict__ sel,
                                   const int* __restrict__ slot,
                                   unsigned char* __restrict__ Xc, float* __restrict__ out) {
  int tokg = blockIdx.x;           // 0..16383
  const float4* src = (const float4*)(x + (size_t)tokg * DIM);
  int t = threadIdx.x;             // 256
  float4 v = src[t];
  if (sel[tokg]) {
    unsigned lo = (unsigned)__builtin_amdgcn_cvt_pk_fp8_f32(v.x, v.y, 0, false);
    unsigned both = (unsigned)__builtin_amdgcn_cvt_pk_fp8_f32(v.z, v.w, (int)lo, true);
    int mrow = slot[tokg];
    int panel = mrow >> 7, rowp = mrow & 127;
    int k = t * 4;
    int pos = kperm(k & 127);      // pos % 4 == 0
    size_t addr = (size_t)panel * (128 * DIM) + (size_t)(k >> 7) * 16384
                + (size_t)(pos >> 5) * 4096 + (size_t)rowp * 32 + (pos & 31);
    *(unsigned*)(Xc + addr) = both;
  } else {
    ((float4*)(out + (size_t)tokg * DIM))[t] = v;
  }
}

// ==== MX-FP8 GEMM: panel-major reg-A + LDS-B, DEPTH-2 counted prefetch ====
// (byte-identical to R19's gemm17 -- GEMM frozen)
template <int EPI>
__global__ __launch_bounds__(256)
void gemm17(const unsigned char* __restrict__ A, const unsigned char* __restrict__ Bt,
            int M, int N, int K,
            const float* __restrict__ bias,
            unsigned char* __restrict__ Hout,
            const float* __restrict__ x,
            const int* __restrict__ rows,
            const float* __restrict__ rwv,
            float* __restrict__ out) {
  __shared__ __align__(16) unsigned char Bs[3][128 * 128];   // 48 KB

  const int t = threadIdx.x;
  const int lane = t & 63;
  const int wid = t >> 6;
  const int wm = wid >> 1;                 // 0..1
  const int wn = wid & 1;                  // 0..1

  // XCD-aware bijective swizzle (gridDim.x % 8 == 0 by construction)
  const int nwg = gridDim.x;
  const int qq = nwg >> 3;
  const int nid = (blockIdx.x & 7) * qq + (blockIdx.x >> 3);
  const int gx = N / 128;
  const int by = nid / gx;
  const int bx = nid - by * gx;
  const int bm0 = by * 128;
  const int bn0 = bx * 128;

  const size_t ldb = (size_t)K;            // row BYTES (fp8)
  const char* Bb = (const char*)Bt + (size_t)bn0 * ldb;

  // B staging: thread t covers 16B of each 32-row chunk; row = t>>3 (0..31),
  // dest slot = t&7, source slot = (t&7)^(row&7)
  const int srow = t >> 3;
  const size_t stage_off = (size_t)srow * ldb + (size_t)((((t & 7) ^ (srow & 7)) * 16));

  // B fragment b128 offsets within a 128B kperm row (swizzled 16B units)
  const int cbs0 = ((lane >> 4) * 32     ) ^ ((lane & 7) << 4);
  const int cbs1 = ((lane >> 4) * 32 + 16) ^ ((lane & 7) << 4);

  // A panel-major fragment bases (panel = by)
  const char* Ap = (const char*)A + (size_t)by * 128 * (size_t)K + (size_t)(lane >> 4) * 4096;
  const char* arow[4];
#pragma unroll
  for (int i = 0; i < 4; ++i)
    arow[i] = Ap + (size_t)(wm * 64 + i * 16 + (lane & 15)) * 32;

  f32x4_t acc[4][4];
  f32x4_t zero = {0.f, 0.f, 0.f, 0.f};
#pragma unroll
  for (int i = 0; i < 4; ++i)
#pragma unroll
    for (int j = 0; j < 4; ++j) acc[i][j] = zero;

  const int NT = K / 128;                  // 8 or 32

  i32x8_t am[3][4];                        // 3 A-register sets (rotated, static idx)

  auto loadA = [&](i32x8_t* dst, int kt) {
#pragma unroll
    for (int i = 0; i < 4; ++i)
      dst[i] = *(const i32x8_t*)(arow[i] + (size_t)kt * 16384);
  };
  auto stageB = [&](int buf, int kt) {
    const size_t kb = (size_t)kt * 128 + stage_off;
    char* dst = (char*)Bs[buf] + t * 16;
#pragma unroll
    for (int c = 0; c < 4; ++c)
      GLD16(Bb + kb + (size_t)(c * 32) * ldb, dst + c * 4096);
  };
  auto compute = [&](const i32x8_t* a, int buf) {
    i32x8_t bq[4];
#pragma unroll
    for (int j = 0; j < 4; ++j) {
      const char* bp = (const char*)Bs[buf] + (wn * 64 + j * 16 + (lane & 15)) * 128;
      union { u64x2_t q[2]; i32x8_t v; } u;
      u.q[0] = *(const u64x2_t*)(bp + cbs0);
      u.q[1] = *(const u64x2_t*)(bp + cbs1);
      bq[j] = u.v;
    }
    __builtin_amdgcn_s_setprio(1);
#pragma unroll
    for (int i = 0; i < 4; ++i)
#pragma unroll
      for (int j = 0; j < 4; ++j)
        acc[i][j] = __builtin_amdgcn_mfma_scale_f32_16x16x128_f8f6f4(
            a[i], bq[j], acc[i][j], 0, 0,
            0, 0x7f7f7f7f, 0, 0x7f7f7f7f);   // E8M0 0x7f = 1.0 scales
    __builtin_amdgcn_s_setprio(0);
  };

  // prologue: tiles 0 and 1 in flight (24 VMEM ops)
  loadA(am[0], 0); stageB(0, 0);
  loadA(am[1], 1); stageB(1, 1);

  for (int kt = 0; kt < NT; kt += 3) {
#pragma unroll
    for (int b = 0; b < 3; ++b) {
      const int T = kt + b;
      if (T < NT) {
        const int nb = (b + 2) % 3;          // compile-time after unroll
        if (T + 2 < NT) {
          loadA(am[nb], T + 2);
          stageB(nb, T + 2);
          asm volatile("s_waitcnt vmcnt(24)" ::: "memory");   // T done; T+1,T+2 in flight
        } else if (T + 1 < NT) {
          asm volatile("s_waitcnt vmcnt(12)" ::: "memory");   // T done; T+1 in flight
        } else {
          asm volatile("s_waitcnt vmcnt(0)" ::: "memory");    // last tile
        }
        __builtin_amdgcn_s_barrier();
        __builtin_amdgcn_sched_barrier(0);
        compute(am[b], b);
        __builtin_amdgcn_s_barrier();
      }
    }
  }

  // epilogue  (C/D: row = (lane>>4)*4 + qi (M), col = lane&15 (N))
  const int rb = (lane >> 4) * 4;
  const int cc = lane & 15;
#pragma unroll
  for (int i = 0; i < 4; ++i) {
#pragma unroll
    for (int qi = 0; qi < 4; ++qi) {
      int grow = bm0 + wm * 64 + i * 16 + rb + qi;
      if (EPI == 1) {
        int panel = grow >> 7, rowp = grow & 127;
#pragma unroll
        for (int j = 0; j < 4; ++j) {
          int gcol = bn0 + wn * 64 + j * 16 + cc;
          float v = acc[i][j][qi] * 0.0625f + bias[gcol];
          float cp = 0.7978845608028654f * (v + 0.044715f * v * v * v);
          float g = v / (1.f + __expf(-2.f * cp));   // tanh-approx gelu
          int pos = kperm(gcol & 127);
          size_t addr = (size_t)panel * (128 * DFF) + (size_t)(gcol >> 7) * 16384
                      + (size_t)(pos >> 5) * 4096 + (size_t)rowp * 32 + (pos & 31);
          Hout[addr] = f2fp8(g);
        }
      } else {
        int batch = grow >> 11;
        int tok = rows[grow];
        float rw = rwv[grow];
        size_t obase = ((size_t)(batch * SEQ + tok)) * DIM;
#pragma unroll
        for (int j = 0; j < 4; ++j) {
          int gcol = bn0 + wn * 64 + j * 16 + cc;
          float v = acc[i][j][qi] * 0.0625f + bias[gcol];
          out[obase + gcol] = x[obase + gcol] + rw * v;
        }
      }
    }
  }
}

extern "C" void kernel_launch(void* const* d_in, const int* in_sizes, int n_in,
                              void* d_out, int out_size, void* d_ws, size_t ws_size,
                              hipStream_t stream) {
  const float* x  = (const float*)d_in[0];
  // d_in[1] = attention_mask (unused by reference)
  const float* Wr = (const float*)d_in[2];
  const float* br = (const float*)d_in[3];
  const float* W1 = (const float*)d_in[4];
  const float* b1 = (const float*)d_in[5];
  const float* W2 = (const float*)d_in[6];
  const float* b2 = (const float*)d_in[7];
  float* out = (float*)d_out;

  char* ws = (char*)d_ws;
  float* logits = (float*)(ws);
  float* scores = (float*)(ws + 65536);
  int*   sel    = (int*)(ws + 131072);
  int*   rows   = (int*)(ws + 196608);
  float* rwv    = (float*)(ws + 229376);
  int*   slot   = (int*)(ws + 262144);
  float* aux_part = (float*)(ws + 327680);                                // 16 B (+pad)
  unsigned char* W1t = (unsigned char*)(ws + 327936);                     // 4 MB
  unsigned char* W2t = (unsigned char*)(ws + 327936 + 4194304);           // 4 MB
  unsigned char* Xc  = (unsigned char*)(ws + 327936 + 2 * 4194304);       // 8 MB
  unsigned char* H   = (unsigned char*)(ws + 327936 + 2 * 4194304 + 8388608);  // 32 MB

  prep_kernel<<<12288, 256, 0, stream>>>(W1, W1t, W2, W2t, x, Wr, br, logits, scores);
  rank_kernel<<<NTOK / 16, 256, 0, stream>>>(scores, sel);
  pack_kernel<<<NB, 1024, 0, stream>>>(scores, sel, logits, rows, rwv, slot, aux_part);
  gather_copy_kernel<<<NTOK, 256, 0, stream>>>(x, sel, slot, Xc, out);
  gemm17<1><<<(MR / 128) * (DFF / 128), 256, 0, stream>>>(
      Xc, W1t, MR, DFF, DIM, b1, H, nullptr, nullptr, nullptr, nullptr);
  gemm17<2><<<(MR / 128) * (DIM / 128), 256, 0, stream>>>(
      H, W2t, MR, DIM, DFF, b2, nullptr, x, rows, rwv, out);
  aux_final<<<1, 64, 0, stream>>>(aux_part, out, out_size);
}